// Round 4
// baseline (2567.095 us; speedup 1.0000x reference)
//
#include <hip/hip_runtime.h>

#define NSAMP 384
#define NCOMBO 60
#define NROW 23040
#define KDIM 512
#define NCLS 7463
#define NCLSP 7680
#define NTILE_N 120
#define NTILE_M 180

typedef short s16x8 __attribute__((ext_vector_type(8)));
typedef float f32x4 __attribute__((ext_vector_type(4)));

// ---- module-level scratch (allocated at .so load; every byte rewritten each call
// before any read on the same stream) ----
__device__ unsigned short g_wc_hi[NCLSP * KDIM];      //  7.86 MB
__device__ unsigned short g_wc_lo[NCLSP * KDIM];      //  7.86 MB
__device__ unsigned short g_h_hi[NROW * KDIM];        // 23.6 MB
__device__ unsigned short g_h_lo[NROW * KDIM];        // 23.6 MB
__device__ unsigned short g_rawbf[NROW * 256];        // 11.8 MB
__device__ float          g_pmax[NROW * NTILE_N];     // 11.0 MB
__device__ int            g_pidx[NROW * NTILE_N];     // 11.0 MB
__device__ float          g_part[10 * NSAMP * 512];   //  7.86 MB

__device__ __forceinline__ float bf2f(unsigned short u){
  union { unsigned int i; float f; } v; v.i = ((unsigned int)u) << 16; return v.f;
}
__device__ __forceinline__ unsigned short f2bf(float f){
  union { float f; unsigned int i; } v; v.f = f;
  unsigned int u = v.i;
  unsigned int r = (u + 0x7FFFu + ((u >> 16) & 1u)) >> 16;
  return (unsigned short)r;
}

// ---------------- K0: split wc (fp32) into bf16 hi/lo, zero-pad classes to 7680 ----
__global__ __launch_bounds__(256) void k_split(const float* __restrict__ wc)
{
  int base = blockIdx.x * 1024 + threadIdx.x;
  #pragma unroll
  for (int e = 0; e < 4; ++e){
    int idx = base + e * 256;                 // < NCLSP*KDIM by grid construction
    float w = 0.f;
    if (idx < NCLS * KDIM) w = wc[idx];
    unsigned short hi = f2bf(w);
    unsigned short lo = f2bf(w - bf2f(hi));
    g_wc_hi[idx] = hi; g_wc_lo[idx] = lo;
  }
}

// ---------------- K1: per-combo features: raw[16][16], h1, h2 -> h hi/lo + raw bf16
__global__ __launch_bounds__(256) void k_features(
    const int* __restrict__ x,
    const float* __restrict__ suit_w, const float* __restrict__ suit_b,
    const float* __restrict__ rank_w, const float* __restrict__ rank_b,
    const float* __restrict__ bns_g, const float* __restrict__ bns_b,
    const float* __restrict__ bns_m, const float* __restrict__ bns_v,
    const float* __restrict__ bnr_g, const float* __restrict__ bnr_b,
    const float* __restrict__ bnr_m, const float* __restrict__ bnr_v,
    const float* __restrict__ w1, const float* __restrict__ b1,
    const float* __restrict__ w2, const float* __restrict__ b2)
{
  __shared__ float raw_s[4][256];
  __shared__ float h1_s[4][512];
  const int tid  = threadIdx.x;
  const int lane = tid & 63;
  const int wv   = tid >> 6;                 // wave = one combo
  const int combo = blockIdx.x * 4 + wv;     // 0..23039
  const int s = combo / 60;
  const int k = combo % 60;
  const int hp = k / 10, bt = k % 10;
  const int HP0[6]  = {0,0,0,1,1,2}, HP1[6] = {1,2,3,2,3,3};
  const int BT0[10] = {4,4,4,4,4,4,5,5,5,6};
  const int BT1[10] = {5,5,5,6,6,7,6,6,7,7};
  const int BT2[10] = {6,7,8,7,8,8,7,8,8,8};
  int cards[5] = {HP0[hp], HP1[hp], BT0[bt], BT1[bt], BT2[bt]};
  const int* xp = x + s * 18;
  int rk[5], st[5];
  #pragma unroll
  for (int c = 0; c < 5; ++c){ rk[c] = xp[2*cards[c]]; st[c] = xp[2*cards[c] + 1]; }

  // raw features: cols 0..10 = rank conv (valid, k=5), cols 11..15 = suit conv
  #pragma unroll
  for (int i = 0; i < 4; ++i){
    int e = lane + 64 * i;
    int o = e >> 4, l = e & 15;
    float v;
    if (l < 11){
      float a = 0.f;
      #pragma unroll
      for (int c = 0; c < 5; ++c){
        int d = rk[c] - l;
        if (d >= 0 && d < 5) a += rank_w[o*25 + c*5 + d];
      }
      a += rank_b[o];
      float inv = bnr_g[o] / sqrtf(bnr_v[o] + 1e-5f);
      v = a * inv + (bnr_b[o] - bnr_m[o] * inv);
    } else {
      int j = l - 11;
      float a = suit_b[o];
      #pragma unroll
      for (int c = 0; c < 5; ++c) if (st[c] == j) a += suit_w[o*5 + c];
      float inv = bns_g[o] / sqrtf(bns_v[o] + 1e-5f);
      v = a * inv + (bns_b[o] - bns_m[o] * inv);
    }
    v = fmaxf(v, 0.f);
    raw_s[wv][e] = v;
    g_rawbf[(size_t)s * 15360 + k * 256 + e] = f2bf(v);
  }
  __syncthreads();
  #pragma unroll
  for (int i = 0; i < 8; ++i){
    int e = lane + 64 * i;
    int o = e >> 5, j = e & 31;
    float a = b1[j];
    #pragma unroll
    for (int l = 0; l < 16; ++l) a += raw_s[wv][o*16 + l] * w1[j*16 + l];
    h1_s[wv][e] = fmaxf(a, 0.f);
  }
  __syncthreads();
  #pragma unroll
  for (int i = 0; i < 8; ++i){
    int e = lane + 64 * i;
    int o = e >> 5, j = e & 31;
    float a = b2[j];
    #pragma unroll
    for (int l = 0; l < 32; ++l) a += h1_s[wv][o*32 + l] * w2[j*32 + l];
    a = fmaxf(a, 0.f);
    unsigned short hi = f2bf(a);
    unsigned short lo = f2bf(a - bf2f(hi));
    g_h_hi[(size_t)combo * 512 + e] = hi;
    g_h_lo[(size_t)combo * 512 + e] = lo;
  }
}

// ---------------- K2: logits GEMM (split-bf16, 3 MFMA/term) + fused per-tile argmax
// Tile 128(M) x 64(N), BK=64; 4 waves in 2x2, each owns a 64x32 quadrant.
// Static LDS: 16+16+8+8 = 48 KB (+2 KB epilogue scratch).
__global__ __launch_bounds__(256) void k_logits(const float* __restrict__ bc)
{
  __shared__ unsigned char Ah[16384];      // 128 rows * 128 B (64 bf16)
  __shared__ unsigned char Al[16384];
  __shared__ unsigned char Bh[8192];       //  64 rows * 128 B
  __shared__ unsigned char Bl[8192];
  __shared__ float cmax[256];              // [128 rows][2 wq]
  __shared__ int   cidx[256];
  const int tid  = threadIdx.x;
  const int lane = tid & 63;
  const int wv   = tid >> 6;
  const int wr   = wv >> 1, wq = wv & 1;
  const int n0 = blockIdx.x * 64;
  const int m0 = blockIdx.y * 128;

  f32x4 acc[4][2];
  #pragma unroll
  for (int i = 0; i < 4; ++i)
    #pragma unroll
    for (int j = 0; j < 2; ++j)
      acc[i][j] = (f32x4){0.f, 0.f, 0.f, 0.f};

  const int srow  = tid & 127;             // A staging row
  const int kg0   = tid >> 7;              // 0..1
  const int srowB = tid & 63;              // B staging row
  const int kgB0  = tid >> 6;              // 0..3
  for (int kc = 0; kc < KDIM; kc += 64){
    __syncthreads();
    #pragma unroll
    for (int ii = 0; ii < 4; ++ii){
      int kg = kg0 + ii * 2;               // 0..7 (8 groups of 8 bf16 = 16 B)
      int loff = srow * 128 + ((kg * 16) ^ ((srow & 7) << 4));   // XOR swizzle
      size_t ga = (size_t)(m0 + srow) * KDIM + kc + kg * 8;
      *(uint4*)(Ah + loff) = *(const uint4*)(g_h_hi + ga);
      *(uint4*)(Al + loff) = *(const uint4*)(g_h_lo + ga);
    }
    #pragma unroll
    for (int ii = 0; ii < 2; ++ii){
      int kg = kgB0 + ii * 4;              // 0..7
      int loff = srowB * 128 + ((kg * 16) ^ ((srowB & 7) << 4));
      size_t gb = (size_t)(n0 + srowB) * KDIM + kc + kg * 8;
      *(uint4*)(Bh + loff) = *(const uint4*)(g_wc_hi + gb);
      *(uint4*)(Bl + loff) = *(const uint4*)(g_wc_lo + gb);
    }
    __syncthreads();
    #pragma unroll
    for (int ks = 0; ks < 2; ++ks){
      int kb = (ks * 4 + (lane >> 4)) * 16;       // byte offset of this lane's k-group
      s16x8 ah[4], al[4];
      #pragma unroll
      for (int i = 0; i < 4; ++i){
        int row = wr * 64 + i * 16 + (lane & 15);
        int off = row * 128 + (kb ^ ((row & 7) << 4));
        ah[i] = *(const s16x8*)(Ah + off);
        al[i] = *(const s16x8*)(Al + off);
      }
      #pragma unroll
      for (int j = 0; j < 2; ++j){
        int col = wq * 32 + j * 16 + (lane & 15);
        int off = col * 128 + (kb ^ ((col & 7) << 4));
        s16x8 bh = *(const s16x8*)(Bh + off);
        s16x8 bl = *(const s16x8*)(Bl + off);
        #pragma unroll
        for (int i = 0; i < 4; ++i){
          acc[i][j] = __builtin_amdgcn_mfma_f32_16x16x32_bf16(ah[i], bh, acc[i][j], 0, 0, 0);
          acc[i][j] = __builtin_amdgcn_mfma_f32_16x16x32_bf16(ah[i], bl, acc[i][j], 0, 0, 0);
          acc[i][j] = __builtin_amdgcn_mfma_f32_16x16x32_bf16(al[i], bh, acc[i][j], 0, 0, 0);
        }
      }
    }
  }
  // epilogue: + bc, per-row argmax over this 64-col tile (ties -> lowest index)
  const int g = lane >> 4;
  #pragma unroll
  for (int i = 0; i < 4; ++i){
    #pragma unroll
    for (int r = 0; r < 4; ++r){
      float bv = -__builtin_inff(); int bi = 0x7FFFFFFF;
      #pragma unroll
      for (int j = 0; j < 2; ++j){
        int col = n0 + wq * 32 + j * 16 + (lane & 15);
        if (col < NCLS){
          float v = acc[i][j][r] + bc[col];
          if (v > bv){ bv = v; bi = col; }
        }
      }
      for (int s = 1; s < 16; s <<= 1){
        float ov = __shfl_xor(bv, s);
        int   oi = __shfl_xor(bi, s);
        if (ov > bv || (ov == bv && oi < bi)){ bv = ov; bi = oi; }
      }
      if ((lane & 15) == 0){
        int rloc = wr * 64 + i * 16 + g * 4 + r;
        cmax[rloc * 2 + wq] = bv;
        cidx[rloc * 2 + wq] = bi;
      }
    }
  }
  __syncthreads();
  if (tid < 128){
    float bv = cmax[tid * 2];     int bi = cidx[tid * 2];
    float v1 = cmax[tid * 2 + 1]; int i1 = cidx[tid * 2 + 1];
    if (v1 > bv || (v1 == bv && i1 < bi)){ bv = v1; bi = i1; }
    size_t row = (size_t)(m0 + tid);
    g_pmax[row * NTILE_N + blockIdx.x] = bv;
    g_pidx[row * NTILE_N + blockIdx.x] = bi;
  }
}

// ---------------- K3: combine tile argmaxes per row, then min over 60 combos ------
__global__ __launch_bounds__(64) void k_best(float* __restrict__ out)
{
  __shared__ int bis[60];
  const int s = blockIdx.x; const int t = threadIdx.x;
  if (t < 60){
    size_t row = (size_t)s * 60 + t;
    float bv = -__builtin_inff(); int bi = 0x7FFFFFFF;
    for (int q = 0; q < NTILE_N; ++q){
      float v = g_pmax[row * NTILE_N + q];
      int   i = g_pidx[row * NTILE_N + q];
      if (v > bv || (v == bv && i < bi)){ bv = v; bi = i; }
    }
    bis[t] = bi;
  }
  __syncthreads();
  if (t == 0){
    int m = bis[0];
    for (int i = 1; i < 60; ++i) m = min(m, bis[i]);
    out[s * 128 + 127] = (float)m;
  }
}

// ---------------- K4: o-head first GEMM, split-K partials (fp32, bf16 A) ----------
__global__ __launch_bounds__(256) void k_o1(const float* __restrict__ wo1)
{
  const int n0 = blockIdx.x * 64;
  const int m0 = blockIdx.y * 64;
  const int q0 = blockIdx.z * 1536;
  const int tid = threadIdx.x;
  const int tr = tid >> 4, tc = tid & 15;
  float acc[4][4];
  #pragma unroll
  for (int r = 0; r < 4; ++r)
    #pragma unroll
    for (int c = 0; c < 4; ++c) acc[r][c] = 0.f;
  const unsigned short* ap = g_rawbf + (size_t)(m0 + tr * 4) * 15360 + q0;
  const float*          bp = wo1     + (size_t)(n0 + tc * 4) * 15360 + q0;
  for (int q = 0; q < 1536; q += 4){
    float av[4][4];
    #pragma unroll
    for (int r = 0; r < 4; ++r){
      ushort4 u = *(const ushort4*)(ap + (size_t)r * 15360 + q);
      av[r][0] = bf2f(u.x); av[r][1] = bf2f(u.y); av[r][2] = bf2f(u.z); av[r][3] = bf2f(u.w);
    }
    #pragma unroll
    for (int c = 0; c < 4; ++c){
      float4 w4 = *(const float4*)(bp + (size_t)c * 15360 + q);
      #pragma unroll
      for (int r = 0; r < 4; ++r)
        acc[r][c] += av[r][0]*w4.x + av[r][1]*w4.y + av[r][2]*w4.z + av[r][3]*w4.w;
    }
  }
  #pragma unroll
  for (int r = 0; r < 4; ++r)
    #pragma unroll
    for (int c = 0; c < 4; ++c)
      g_part[((size_t)blockIdx.z * NSAMP + m0 + tr*4 + r) * 512 + n0 + tc*4 + c] = acc[r][c];
}

// ---------------- K5: o-head tail: reduce split-K, relu, 512->256->127, write out -
__global__ __launch_bounds__(256) void k_otail(
    const float* __restrict__ bo1, const float* __restrict__ wo2,
    const float* __restrict__ bo2, const float* __restrict__ wo3,
    const float* __restrict__ bo3, float* __restrict__ out)
{
  __shared__ float o1f[512];
  __shared__ float o2f[256];
  const int s = blockIdx.x;
  const int tid = threadIdx.x;
  for (int j = tid; j < 512; j += 256){
    float a = bo1[j];
    for (int ks = 0; ks < 10; ++ks) a += g_part[((size_t)ks * NSAMP + s) * 512 + j];
    o1f[j] = fmaxf(a, 0.f);
  }
  __syncthreads();
  {
    float a = bo2[tid];
    const float* wr = wo2 + (size_t)tid * 512;
    for (int i = 0; i < 512; i += 4){
      float4 w4 = *(const float4*)(wr + i);
      a += o1f[i]*w4.x + o1f[i+1]*w4.y + o1f[i+2]*w4.z + o1f[i+3]*w4.w;
    }
    o2f[tid] = fmaxf(a, 0.f);
  }
  __syncthreads();
  if (tid < 127){
    float a = bo3[tid];
    const float* wr = wo3 + (size_t)tid * 256;
    for (int i = 0; i < 256; i += 4){
      float4 w4 = *(const float4*)(wr + i);
      a += o2f[i]*w4.x + o2f[i+1]*w4.y + o2f[i+2]*w4.z + o2f[i+3]*w4.w;
    }
    out[s * 128 + tid] = fmaxf(a, 0.f);
  }
}

extern "C" void kernel_launch(void* const* d_in, const int* in_sizes, int n_in,
                              void* d_out, int out_size, void* d_ws, size_t ws_size,
                              hipStream_t stream)
{
  (void)d_ws; (void)ws_size; (void)in_sizes; (void)n_in; (void)out_size;
  const int*   x      = (const int*)  d_in[0];
  const float* suit_w = (const float*)d_in[1];
  const float* suit_b = (const float*)d_in[2];
  const float* rank_w = (const float*)d_in[3];
  const float* rank_b = (const float*)d_in[4];
  const float* bns_g  = (const float*)d_in[5];
  const float* bns_b  = (const float*)d_in[6];
  const float* bns_m  = (const float*)d_in[7];
  const float* bns_v  = (const float*)d_in[8];
  const float* bnr_g  = (const float*)d_in[9];
  const float* bnr_b  = (const float*)d_in[10];
  const float* bnr_m  = (const float*)d_in[11];
  const float* bnr_v  = (const float*)d_in[12];
  const float* w1     = (const float*)d_in[13];
  const float* b1     = (const float*)d_in[14];
  const float* w2     = (const float*)d_in[15];
  const float* b2     = (const float*)d_in[16];
  const float* wc     = (const float*)d_in[17];
  const float* bc     = (const float*)d_in[18];
  const float* wo1    = (const float*)d_in[19];
  const float* bo1    = (const float*)d_in[20];
  const float* wo2    = (const float*)d_in[21];
  const float* bo2    = (const float*)d_in[22];
  const float* wo3    = (const float*)d_in[23];
  const float* bo3    = (const float*)d_in[24];
  float* out = (float*)d_out;

  hipLaunchKernelGGL(k_split, dim3(3840), dim3(256), 0, stream, wc);
  hipLaunchKernelGGL(k_features, dim3(5760), dim3(256), 0, stream, x,
                     suit_w, suit_b, rank_w, rank_b,
                     bns_g, bns_b, bns_m, bns_v, bnr_g, bnr_b, bnr_m, bnr_v,
                     w1, b1, w2, b2);
  hipLaunchKernelGGL(k_logits, dim3(NTILE_N, NTILE_M), dim3(256), 0, stream, bc);
  hipLaunchKernelGGL(k_best, dim3(NSAMP), dim3(64), 0, stream, out);
  hipLaunchKernelGGL(k_o1, dim3(8, 6, 10), dim3(256), 0, stream, wo1);
  hipLaunchKernelGGL(k_otail, dim3(NSAMP), dim3(256), 0, stream,
                     bo1, wo2, bo2, wo3, bo3, out);
}

// Round 5
// 1455.421 us; speedup vs baseline: 1.7638x; 1.7638x over previous
//
#include <hip/hip_runtime.h>

#define NSAMP 384
#define NCOMBO 60
#define NROW 23040
#define KDIM 512
#define NCLS 7463
#define NCLSP 7680
#define NTILE_N 60
#define NTILE_M 180
#define O1_NZ 30
#define O1_KZ 512

typedef short s16x8 __attribute__((ext_vector_type(8)));
typedef float f32x4 __attribute__((ext_vector_type(4)));

// ---- module-level scratch (every byte rewritten each call before any read) ----
__device__ unsigned short g_wc_hi[NCLSP * KDIM];
__device__ unsigned short g_wc_lo[NCLSP * KDIM];
__device__ unsigned short g_h_hi[NROW * KDIM];
__device__ unsigned short g_h_lo[NROW * KDIM];
__device__ unsigned short g_rawbf[NROW * 256];          // == [NSAMP][15360]
__device__ unsigned short g_wo1bf[512 * 15360];
__device__ float          g_pmax[NROW * NTILE_N];
__device__ int            g_pidx[NROW * NTILE_N];
__device__ float          g_part[O1_NZ * NSAMP * 512];

__device__ __forceinline__ float bf2f(unsigned short u){
  union { unsigned int i; float f; } v; v.i = ((unsigned int)u) << 16; return v.f;
}
__device__ __forceinline__ unsigned short f2bf(float f){
  union { float f; unsigned int i; } v; v.f = f;
  unsigned int u = v.i;
  unsigned int r = (u + 0x7FFFu + ((u >> 16) & 1u)) >> 16;
  return (unsigned short)r;
}
// async global->LDS, 16B per lane; LDS dest must be wave-uniform base (HW adds lane*16)
__device__ __forceinline__ void gload16(const void* g, void* l){
  __builtin_amdgcn_global_load_lds((const __attribute__((address_space(1))) void*)g,
                                   (__attribute__((address_space(3))) void*)l, 16, 0, 0);
}

// ---------------- K0: split wc (fp32) into bf16 hi/lo, zero-pad classes to 7680 ----
__global__ __launch_bounds__(256) void k_split(const float* __restrict__ wc)
{
  int base = blockIdx.x * 1024 + threadIdx.x;
  #pragma unroll
  for (int e = 0; e < 4; ++e){
    int idx = base + e * 256;
    float w = 0.f;
    if (idx < NCLS * KDIM) w = wc[idx];
    unsigned short hi = f2bf(w);
    unsigned short lo = f2bf(w - bf2f(hi));
    g_wc_hi[idx] = hi; g_wc_lo[idx] = lo;
  }
}

// ---------------- K0b: wo1 -> bf16 ----------------
__global__ __launch_bounds__(256) void k_splitw(const float* __restrict__ wo1)
{
  int base = blockIdx.x * 1024 + threadIdx.x;
  #pragma unroll
  for (int e = 0; e < 4; ++e){
    int idx = base + e * 256;               // grid covers 512*15360 exactly
    g_wo1bf[idx] = f2bf(wo1[idx]);
  }
}

// ---------------- K1: per-combo features -> h hi/lo + raw bf16 ----------------
__global__ __launch_bounds__(256) void k_features(
    const int* __restrict__ x,
    const float* __restrict__ suit_w, const float* __restrict__ suit_b,
    const float* __restrict__ rank_w, const float* __restrict__ rank_b,
    const float* __restrict__ bns_g, const float* __restrict__ bns_b,
    const float* __restrict__ bns_m, const float* __restrict__ bns_v,
    const float* __restrict__ bnr_g, const float* __restrict__ bnr_b,
    const float* __restrict__ bnr_m, const float* __restrict__ bnr_v,
    const float* __restrict__ w1, const float* __restrict__ b1,
    const float* __restrict__ w2, const float* __restrict__ b2)
{
  __shared__ float raw_s[4][256];
  __shared__ float h1_s[4][512];
  const int tid  = threadIdx.x;
  const int lane = tid & 63;
  const int wv   = tid >> 6;
  const int combo = blockIdx.x * 4 + wv;
  const int s = combo / 60;
  const int k = combo % 60;
  const int hp = k / 10, bt = k % 10;
  const int HP0[6]  = {0,0,0,1,1,2}, HP1[6] = {1,2,3,2,3,3};
  const int BT0[10] = {4,4,4,4,4,4,5,5,5,6};
  const int BT1[10] = {5,5,5,6,6,7,6,6,7,7};
  const int BT2[10] = {6,7,8,7,8,8,7,8,8,8};
  int cards[5] = {HP0[hp], HP1[hp], BT0[bt], BT1[bt], BT2[bt]};
  const int* xp = x + s * 18;
  int rk[5], st[5];
  #pragma unroll
  for (int c = 0; c < 5; ++c){ rk[c] = xp[2*cards[c]]; st[c] = xp[2*cards[c] + 1]; }

  #pragma unroll
  for (int i = 0; i < 4; ++i){
    int e = lane + 64 * i;
    int o = e >> 4, l = e & 15;
    float v;
    if (l < 11){
      float a = 0.f;
      #pragma unroll
      for (int c = 0; c < 5; ++c){
        int d = rk[c] - l;
        if (d >= 0 && d < 5) a += rank_w[o*25 + c*5 + d];
      }
      a += rank_b[o];
      float inv = bnr_g[o] / sqrtf(bnr_v[o] + 1e-5f);
      v = a * inv + (bnr_b[o] - bnr_m[o] * inv);
    } else {
      int j = l - 11;
      float a = suit_b[o];
      #pragma unroll
      for (int c = 0; c < 5; ++c) if (st[c] == j) a += suit_w[o*5 + c];
      float inv = bns_g[o] / sqrtf(bns_v[o] + 1e-5f);
      v = a * inv + (bns_b[o] - bns_m[o] * inv);
    }
    v = fmaxf(v, 0.f);
    raw_s[wv][e] = v;
    g_rawbf[(size_t)s * 15360 + k * 256 + e] = f2bf(v);
  }
  __syncthreads();
  #pragma unroll
  for (int i = 0; i < 8; ++i){
    int e = lane + 64 * i;
    int o = e >> 5, j = e & 31;
    float a = b1[j];
    #pragma unroll
    for (int l = 0; l < 16; ++l) a += raw_s[wv][o*16 + l] * w1[j*16 + l];
    h1_s[wv][e] = fmaxf(a, 0.f);
  }
  __syncthreads();
  #pragma unroll
  for (int i = 0; i < 8; ++i){
    int e = lane + 64 * i;
    int o = e >> 5, j = e & 31;
    float a = b2[j];
    #pragma unroll
    for (int l = 0; l < 32; ++l) a += h1_s[wv][o*32 + l] * w2[j*32 + l];
    a = fmaxf(a, 0.f);
    unsigned short hi = f2bf(a);
    unsigned short lo = f2bf(a - bf2f(hi));
    g_h_hi[(size_t)combo * 512 + e] = hi;
    g_h_lo[(size_t)combo * 512 + e] = lo;
  }
}

// ---------------- K2: logits GEMM (split-bf16, 3 MFMA) + fused per-tile argmax ----
// 128x128 tile, BK=64, 4 waves in 2x2 (each 64x64 out). global_load_lds staging:
// linear LDS dest, inverse-swizzled global source, XOR-swizzled ds_read (rule #21).
__global__ __launch_bounds__(256) void k_logits(const float* __restrict__ bc)
{
  __shared__ unsigned char Ah[16384];   // [128 rows][128B], chunk c holds global chunk c^(r&7)
  __shared__ unsigned char Al[16384];
  __shared__ unsigned char Bh[16384];
  __shared__ unsigned char Bl[16384];
  const int tid  = threadIdx.x;
  const int lane = tid & 63;
  const int wv   = tid >> 6;
  const int wr   = wv >> 1, wq = wv & 1;
  const int n0 = blockIdx.x * 128;
  const int m0 = blockIdx.y * 128;

  f32x4 acc[4][4];
  #pragma unroll
  for (int i = 0; i < 4; ++i)
    #pragma unroll
    for (int j = 0; j < 4; ++j)
      acc[i][j] = (f32x4){0.f, 0.f, 0.f, 0.f};

  const int rA = lane >> 3;       // row within 8-row segment
  const int c0 = lane & 7;        // dest chunk
  for (int kc = 0; kc < KDIM; kc += 64){
    __syncthreads();
    #pragma unroll
    for (int it = 0; it < 4; ++it){
      int seg = wv * 4 + it;                 // wave-uniform
      int r   = seg * 8 + rA;
      int cs  = c0 ^ (r & 7);                // pre-swizzled source chunk
      size_t goffA = (size_t)(m0 + r) * KDIM + kc + cs * 8;
      size_t goffB = (size_t)(n0 + r) * KDIM + kc + cs * 8;
      unsigned lb = seg * 1024;
      gload16(g_h_hi  + goffA, Ah + lb);
      gload16(g_h_lo  + goffA, Al + lb);
      gload16(g_wc_hi + goffB, Bh + lb);
      gload16(g_wc_lo + goffB, Bl + lb);
    }
    __syncthreads();                          // compiler drains vmcnt(0) here
    #pragma unroll
    for (int ks = 0; ks < 2; ++ks){
      int q = ks * 4 + (lane >> 4);          // 8-element k-chunk index within BK
      s16x8 a_h[4], a_l[4];
      #pragma unroll
      for (int i = 0; i < 4; ++i){
        int row = wr * 64 + i * 16 + (lane & 15);
        int off = row * 128 + ((q ^ (row & 7)) * 16);
        a_h[i] = *(const s16x8*)(Ah + off);
        a_l[i] = *(const s16x8*)(Al + off);
      }
      #pragma unroll
      for (int j = 0; j < 4; ++j){
        int col = wq * 64 + j * 16 + (lane & 15);
        int off = col * 128 + ((q ^ (col & 7)) * 16);
        s16x8 b_h = *(const s16x8*)(Bh + off);
        s16x8 b_l = *(const s16x8*)(Bl + off);
        #pragma unroll
        for (int i = 0; i < 4; ++i){
          acc[i][j] = __builtin_amdgcn_mfma_f32_16x16x32_bf16(a_h[i], b_h, acc[i][j], 0, 0, 0);
          acc[i][j] = __builtin_amdgcn_mfma_f32_16x16x32_bf16(a_h[i], b_l, acc[i][j], 0, 0, 0);
          acc[i][j] = __builtin_amdgcn_mfma_f32_16x16x32_bf16(a_l[i], b_h, acc[i][j], 0, 0, 0);
        }
      }
    }
  }
  __syncthreads();
  // epilogue: + bc, per-row argmax over this 128-col tile (ties -> lowest index)
  float* cmax = (float*)Ah;                  // [128][2]
  int*   cidx = (int*)Bh;
  const int g = lane >> 4;
  #pragma unroll
  for (int i = 0; i < 4; ++i){
    #pragma unroll
    for (int r = 0; r < 4; ++r){
      float bv = -__builtin_inff(); int bi = 0x7FFFFFFF;
      #pragma unroll
      for (int j = 0; j < 4; ++j){
        int col = n0 + wq * 64 + j * 16 + (lane & 15);
        if (col < NCLS){
          float v = acc[i][j][r] + bc[col];
          if (v > bv){ bv = v; bi = col; }
        }
      }
      for (int s = 1; s < 16; s <<= 1){
        float ov = __shfl_xor(bv, s);
        int   oi = __shfl_xor(bi, s);
        if (ov > bv || (ov == bv && oi < bi)){ bv = ov; bi = oi; }
      }
      if ((lane & 15) == 0){
        int rloc = wr * 64 + i * 16 + g * 4 + r;
        cmax[rloc * 2 + wq] = bv;
        cidx[rloc * 2 + wq] = bi;
      }
    }
  }
  __syncthreads();
  if (tid < 128){
    float bv = cmax[tid * 2];     int bi = cidx[tid * 2];
    float v1 = cmax[tid * 2 + 1]; int i1 = cidx[tid * 2 + 1];
    if (v1 > bv || (v1 == bv && i1 < bi)){ bv = v1; bi = i1; }
    size_t row = (size_t)(m0 + tid);
    g_pmax[row * NTILE_N + blockIdx.x] = bv;
    g_pidx[row * NTILE_N + blockIdx.x] = bi;
  }
}

// ---------------- K3: combine tile argmaxes per row, then min over 60 combos ------
__global__ __launch_bounds__(64) void k_best(float* __restrict__ out)
{
  __shared__ int bis[60];
  const int s = blockIdx.x; const int t = threadIdx.x;
  if (t < 60){
    size_t row = (size_t)s * 60 + t;
    float bv = -__builtin_inff(); int bi = 0x7FFFFFFF;
    for (int q = 0; q < NTILE_N; ++q){
      float v = g_pmax[row * NTILE_N + q];
      int   i = g_pidx[row * NTILE_N + q];
      if (v > bv || (v == bv && i < bi)){ bv = v; bi = i; }
    }
    bis[t] = bi;
  }
  __syncthreads();
  if (t == 0){
    int m = bis[0];
    for (int i = 1; i < 60; ++i) m = min(m, bis[i]);
    out[s * 128 + 127] = (float)m;
  }
}

// ---------------- K4: o-head first GEMM via MFMA (bf16), split-K z=30 -------------
// C[384x512] = rawbf[384x15360] . wo1bf^T ; 128x128 tile, per-block K-chunk 512.
__global__ __launch_bounds__(256) void k_o1(void)
{
  __shared__ unsigned char As[16384];
  __shared__ unsigned char Bs[16384];
  const int tid  = threadIdx.x;
  const int lane = tid & 63;
  const int wv   = tid >> 6;
  const int wr   = wv >> 1, wq = wv & 1;
  const int n0  = blockIdx.x * 128;          // 4
  const int m0  = blockIdx.y * 128;          // 3
  const int kc0 = blockIdx.z * O1_KZ;        // 30

  f32x4 acc[4][4];
  #pragma unroll
  for (int i = 0; i < 4; ++i)
    #pragma unroll
    for (int j = 0; j < 4; ++j)
      acc[i][j] = (f32x4){0.f, 0.f, 0.f, 0.f};

  const int rA = lane >> 3;
  const int c0 = lane & 7;
  for (int kk = 0; kk < O1_KZ; kk += 64){
    int kc = kc0 + kk;
    __syncthreads();
    #pragma unroll
    for (int it = 0; it < 4; ++it){
      int seg = wv * 4 + it;
      int r   = seg * 8 + rA;
      int cs  = c0 ^ (r & 7);
      gload16(g_rawbf + (size_t)(m0 + r) * 15360 + kc + cs * 8, As + seg * 1024);
      gload16(g_wo1bf + (size_t)(n0 + r) * 15360 + kc + cs * 8, Bs + seg * 1024);
    }
    __syncthreads();
    #pragma unroll
    for (int ks = 0; ks < 2; ++ks){
      int q = ks * 4 + (lane >> 4);
      s16x8 a[4];
      #pragma unroll
      for (int i = 0; i < 4; ++i){
        int row = wr * 64 + i * 16 + (lane & 15);
        a[i] = *(const s16x8*)(As + row * 128 + ((q ^ (row & 7)) * 16));
      }
      #pragma unroll
      for (int j = 0; j < 4; ++j){
        int col = wq * 64 + j * 16 + (lane & 15);
        s16x8 b = *(const s16x8*)(Bs + col * 128 + ((q ^ (col & 7)) * 16));
        #pragma unroll
        for (int i = 0; i < 4; ++i)
          acc[i][j] = __builtin_amdgcn_mfma_f32_16x16x32_bf16(a[i], b, acc[i][j], 0, 0, 0);
      }
    }
  }
  const int g = lane >> 4;
  #pragma unroll
  for (int i = 0; i < 4; ++i)
    #pragma unroll
    for (int j = 0; j < 4; ++j)
      #pragma unroll
      for (int r = 0; r < 4; ++r){
        int gm = m0 + wr * 64 + i * 16 + g * 4 + r;
        int gn = n0 + wq * 64 + j * 16 + (lane & 15);
        g_part[((size_t)blockIdx.z * NSAMP + gm) * 512 + gn] = acc[i][j][r];
      }
}

// ---------------- K5: o-head tail: reduce split-K, relu, 512->256->127 ------------
__global__ __launch_bounds__(256) void k_otail(
    const float* __restrict__ bo1, const float* __restrict__ wo2,
    const float* __restrict__ bo2, const float* __restrict__ wo3,
    const float* __restrict__ bo3, float* __restrict__ out)
{
  __shared__ float o1f[512];
  __shared__ float o2f[256];
  const int s = blockIdx.x;
  const int tid = threadIdx.x;
  for (int j = tid; j < 512; j += 256){
    float a = bo1[j];
    for (int ks = 0; ks < O1_NZ; ++ks) a += g_part[((size_t)ks * NSAMP + s) * 512 + j];
    o1f[j] = fmaxf(a, 0.f);
  }
  __syncthreads();
  {
    float a = bo2[tid];
    const float* wr = wo2 + (size_t)tid * 512;
    for (int i = 0; i < 512; i += 4){
      float4 w4 = *(const float4*)(wr + i);
      a += o1f[i]*w4.x + o1f[i+1]*w4.y + o1f[i+2]*w4.z + o1f[i+3]*w4.w;
    }
    o2f[tid] = fmaxf(a, 0.f);
  }
  __syncthreads();
  if (tid < 127){
    float a = bo3[tid];
    const float* wr = wo3 + (size_t)tid * 256;
    for (int i = 0; i < 256; i += 4){
      float4 w4 = *(const float4*)(wr + i);
      a += o2f[i]*w4.x + o2f[i+1]*w4.y + o2f[i+2]*w4.z + o2f[i+3]*w4.w;
    }
    out[s * 128 + tid] = fmaxf(a, 0.f);
  }
}

extern "C" void kernel_launch(void* const* d_in, const int* in_sizes, int n_in,
                              void* d_out, int out_size, void* d_ws, size_t ws_size,
                              hipStream_t stream)
{
  (void)d_ws; (void)ws_size; (void)in_sizes; (void)n_in; (void)out_size;
  const int*   x      = (const int*)  d_in[0];
  const float* suit_w = (const float*)d_in[1];
  const float* suit_b = (const float*)d_in[2];
  const float* rank_w = (const float*)d_in[3];
  const float* rank_b = (const float*)d_in[4];
  const float* bns_g  = (const float*)d_in[5];
  const float* bns_b  = (const float*)d_in[6];
  const float* bns_m  = (const float*)d_in[7];
  const float* bns_v  = (const float*)d_in[8];
  const float* bnr_g  = (const float*)d_in[9];
  const float* bnr_b  = (const float*)d_in[10];
  const float* bnr_m  = (const float*)d_in[11];
  const float* bnr_v  = (const float*)d_in[12];
  const float* w1     = (const float*)d_in[13];
  const float* b1     = (const float*)d_in[14];
  const float* w2     = (const float*)d_in[15];
  const float* b2     = (const float*)d_in[16];
  const float* wc     = (const float*)d_in[17];
  const float* bc     = (const float*)d_in[18];
  const float* wo1    = (const float*)d_in[19];
  const float* bo1    = (const float*)d_in[20];
  const float* wo2    = (const float*)d_in[21];
  const float* bo2    = (const float*)d_in[22];
  const float* wo3    = (const float*)d_in[23];
  const float* bo3    = (const float*)d_in[24];
  float* out = (float*)d_out;

  hipLaunchKernelGGL(k_split,  dim3(3840), dim3(256), 0, stream, wc);
  hipLaunchKernelGGL(k_splitw, dim3(7680), dim3(256), 0, stream, wo1);
  hipLaunchKernelGGL(k_features, dim3(5760), dim3(256), 0, stream, x,
                     suit_w, suit_b, rank_w, rank_b,
                     bns_g, bns_b, bns_m, bns_v, bnr_g, bnr_b, bnr_m, bnr_v,
                     w1, b1, w2, b2);
  hipLaunchKernelGGL(k_logits, dim3(NTILE_N, NTILE_M), dim3(256), 0, stream, bc);
  hipLaunchKernelGGL(k_best, dim3(NSAMP), dim3(64), 0, stream, out);
  hipLaunchKernelGGL(k_o1, dim3(4, 3, O1_NZ), dim3(256), 0, stream);
  hipLaunchKernelGGL(k_otail, dim3(NSAMP), dim3(256), 0, stream,
                     bo1, wo2, bo2, wo3, bo3, out);
}

// Round 6
// 1329.879 us; speedup vs baseline: 1.9303x; 1.0944x over previous
//
#include <hip/hip_runtime.h>

#define NSAMP 384
#define NCOMBO 60
#define NROW 23040
#define KDIM 512
#define NCLS 7463
#define NCLSP 7680
#define NTILE_N 60
#define NTILE_M 180
#define O1_NZ 30
#define O1_KZ 512

typedef short s16x8 __attribute__((ext_vector_type(8)));
typedef short s16x4 __attribute__((ext_vector_type(4)));
typedef float f32x4 __attribute__((ext_vector_type(4)));

// ---- module-level scratch (every byte rewritten each call before any read) ----
__device__ unsigned short g_wc_hi[NCLSP * KDIM];
__device__ unsigned short g_wc_lo[NCLSP * KDIM];
__device__ unsigned short g_h_hi[NROW * KDIM];
__device__ unsigned short g_h_lo[NROW * KDIM];
__device__ unsigned short g_rawbf[NROW * 256];          // == [NSAMP][15360]
__device__ unsigned short g_wo1bf[512 * 15360];
__device__ float          g_pmax[NROW * NTILE_N];
__device__ int            g_pidx[NROW * NTILE_N];
__device__ float          g_part[O1_NZ * NSAMP * 512];

__device__ __forceinline__ float bf2f(unsigned short u){
  union { unsigned int i; float f; } v; v.i = ((unsigned int)u) << 16; return v.f;
}
__device__ __forceinline__ unsigned short f2bf(float f){
  union { float f; unsigned int i; } v; v.f = f;
  unsigned int u = v.i;
  unsigned int r = (u + 0x7FFFu + ((u >> 16) & 1u)) >> 16;
  return (unsigned short)r;
}
__device__ __forceinline__ void gload16(const void* g, void* l){
  __builtin_amdgcn_global_load_lds((const __attribute__((address_space(1))) void*)g,
                                   (__attribute__((address_space(3))) void*)l, 16, 0, 0);
}

// ---------------- K0: split wc into bf16 hi/lo, zero-pad to 7680 (vectorized) -----
__global__ __launch_bounds__(256) void k_split(const float* __restrict__ wc)
{
  int idx = (blockIdx.x * 256 + threadIdx.x) * 4;    // grid 3840 -> covers NCLSP*KDIM
  float4 w = {0.f, 0.f, 0.f, 0.f};
  if (idx < NCLS * KDIM) w = *(const float4*)(wc + idx);   // boundary is 4-aligned
  s16x4 hi, lo;
  float wv[4] = {w.x, w.y, w.z, w.w};
  #pragma unroll
  for (int i = 0; i < 4; ++i){
    unsigned short h = f2bf(wv[i]);
    hi[i] = (short)h;
    lo[i] = (short)f2bf(wv[i] - bf2f(h));
  }
  *(s16x4*)(g_wc_hi + idx) = hi;
  *(s16x4*)(g_wc_lo + idx) = lo;
}

// ---------------- K0b: wo1 -> bf16 (vectorized) ----------------
__global__ __launch_bounds__(256) void k_splitw(const float* __restrict__ wo1)
{
  int idx = (blockIdx.x * 256 + threadIdx.x) * 4;    // grid 7680 -> 512*15360 exactly
  float4 w = *(const float4*)(wo1 + idx);
  s16x4 b;
  b[0] = (short)f2bf(w.x); b[1] = (short)f2bf(w.y);
  b[2] = (short)f2bf(w.z); b[3] = (short)f2bf(w.w);
  *(s16x4*)(g_wo1bf + idx) = b;
}

// ---------------- K1: per-combo features -> h hi/lo + raw bf16 ----------------
__global__ __launch_bounds__(256) void k_features(
    const int* __restrict__ x,
    const float* __restrict__ suit_w, const float* __restrict__ suit_b,
    const float* __restrict__ rank_w, const float* __restrict__ rank_b,
    const float* __restrict__ bns_g, const float* __restrict__ bns_b,
    const float* __restrict__ bns_m, const float* __restrict__ bns_v,
    const float* __restrict__ bnr_g, const float* __restrict__ bnr_b,
    const float* __restrict__ bnr_m, const float* __restrict__ bnr_v,
    const float* __restrict__ w1, const float* __restrict__ b1,
    const float* __restrict__ w2, const float* __restrict__ b2)
{
  __shared__ float raw_s[4][256];
  __shared__ float h1_s[4][512];
  const int tid  = threadIdx.x;
  const int lane = tid & 63;
  const int wv   = tid >> 6;
  const int combo = blockIdx.x * 4 + wv;
  const int s = combo / 60;
  const int k = combo % 60;
  const int hp = k / 10, bt = k % 10;
  const int HP0[6]  = {0,0,0,1,1,2}, HP1[6] = {1,2,3,2,3,3};
  const int BT0[10] = {4,4,4,4,4,4,5,5,5,6};
  const int BT1[10] = {5,5,5,6,6,7,6,6,7,7};
  const int BT2[10] = {6,7,8,7,8,8,7,8,8,8};
  int cards[5] = {HP0[hp], HP1[hp], BT0[bt], BT1[bt], BT2[bt]};
  const int* xp = x + s * 18;
  int rk[5], st[5];
  #pragma unroll
  for (int c = 0; c < 5; ++c){ rk[c] = xp[2*cards[c]]; st[c] = xp[2*cards[c] + 1]; }

  // raw features: lane owns 4 consecutive elements -> one 8B store
  {
    s16x4 rv;
    #pragma unroll
    for (int i = 0; i < 4; ++i){
      int e = lane * 4 + i;
      int o = e >> 4, l = e & 15;
      float v;
      if (l < 11){
        float a = 0.f;
        #pragma unroll
        for (int c = 0; c < 5; ++c){
          int d = rk[c] - l;
          if (d >= 0 && d < 5) a += rank_w[o*25 + c*5 + d];
        }
        a += rank_b[o];
        float inv = bnr_g[o] / sqrtf(bnr_v[o] + 1e-5f);
        v = a * inv + (bnr_b[o] - bnr_m[o] * inv);
      } else {
        int j = l - 11;
        float a = suit_b[o];
        #pragma unroll
        for (int c = 0; c < 5; ++c) if (st[c] == j) a += suit_w[o*5 + c];
        float inv = bns_g[o] / sqrtf(bns_v[o] + 1e-5f);
        v = a * inv + (bns_b[o] - bns_m[o] * inv);
      }
      v = fmaxf(v, 0.f);
      raw_s[wv][e] = v;
      rv[i] = (short)f2bf(v);
    }
    *(s16x4*)(g_rawbf + (size_t)s * 15360 + k * 256 + lane * 4) = rv;
  }
  __syncthreads();
  #pragma unroll
  for (int i = 0; i < 8; ++i){
    int e = lane + 64 * i;
    int o = e >> 5, j = e & 31;
    float a = b1[j];
    #pragma unroll
    for (int l = 0; l < 16; ++l) a += raw_s[wv][o*16 + l] * w1[j*16 + l];
    h1_s[wv][e] = fmaxf(a, 0.f);
  }
  __syncthreads();
  // h2: lane owns 8 consecutive elements -> one 16B store per array
  {
    s16x8 hv, lv;
    #pragma unroll
    for (int i = 0; i < 8; ++i){
      int e = lane * 8 + i;
      int o = e >> 5, j = e & 31;
      float a = b2[j];
      #pragma unroll
      for (int l = 0; l < 32; ++l) a += h1_s[wv][o*32 + l] * w2[j*32 + l];
      a = fmaxf(a, 0.f);
      unsigned short h = f2bf(a);
      hv[i] = (short)h;
      lv[i] = (short)f2bf(a - bf2f(h));
    }
    *(s16x8*)(g_h_hi + (size_t)combo * 512 + lane * 8) = hv;
    *(s16x8*)(g_h_lo + (size_t)combo * 512 + lane * 8) = lv;
  }
}

// ---------------- K2: logits GEMM (split-bf16, 3 MFMA) + fused per-tile argmax ----
// 128x128 tile, BK=32 (LDS 32KB -> 4 blocks/CU), M-major block order for B-panel
// L2 residency. Staging: linear LDS dest + inverse-swizzled global source; reads
// ds_read_b128 with chunk swizzle q ^ ((row>>1)&3) (<=2-way conflicts).
__global__ __launch_bounds__(256, 4) void k_logits(const float* __restrict__ bc)
{
  __shared__ unsigned char Ah[8192];   // [128 rows][64B]
  __shared__ unsigned char Al[8192];
  __shared__ unsigned char Bh[8192];
  __shared__ unsigned char Bl[8192];
  __shared__ float cmax[256];
  __shared__ int   cidx[256];
  const int tid  = threadIdx.x;
  const int lane = tid & 63;
  const int wv   = tid >> 6;
  const int wr   = wv >> 1, wq = wv & 1;
  const int flat = blockIdx.x;              // 10800 = 60 N-tiles x 180 M-tiles
  const int m0 = (flat % NTILE_M) * 128;    // M-major: consecutive blocks share B
  const int n0 = (flat / NTILE_M) * 128;
  const int ntile = flat / NTILE_M;

  f32x4 acc[4][4];
  #pragma unroll
  for (int i = 0; i < 4; ++i)
    #pragma unroll
    for (int j = 0; j < 4; ++j)
      acc[i][j] = (f32x4){0.f, 0.f, 0.f, 0.f};

  const int rA = lane >> 2;                 // row within 16-row segment
  const int c0 = lane & 3;                  // dest chunk (16B units)
  for (int kc = 0; kc < KDIM; kc += 32){
    __syncthreads();
    #pragma unroll
    for (int it = 0; it < 2; ++it){
      int seg = wv * 2 + it;                // wave-uniform, 0..7
      int r   = seg * 16 + rA;              // 0..127
      int cs  = c0 ^ ((rA >> 1) & 3);       // pre-swizzled source chunk
      size_t gA = (size_t)(m0 + r) * KDIM + kc + cs * 8;
      size_t gB = (size_t)(n0 + r) * KDIM + kc + cs * 8;
      unsigned lb = seg * 1024;
      gload16(g_h_hi  + gA, Ah + lb);
      gload16(g_h_lo  + gA, Al + lb);
      gload16(g_wc_hi + gB, Bh + lb);
      gload16(g_wc_lo + gB, Bl + lb);
    }
    __syncthreads();
    const int q = lane >> 4;                // 8-elem k-chunk 0..3
    s16x8 a_h[4], a_l[4];
    #pragma unroll
    for (int i = 0; i < 4; ++i){
      int row = wr * 64 + i * 16 + (lane & 15);
      int off = row * 64 + ((q ^ ((row >> 1) & 3)) * 16);
      a_h[i] = *(const s16x8*)(Ah + off);
      a_l[i] = *(const s16x8*)(Al + off);
    }
    #pragma unroll
    for (int j = 0; j < 4; ++j){
      int col = wq * 64 + j * 16 + (lane & 15);
      int off = col * 64 + ((q ^ ((col >> 1) & 3)) * 16);
      s16x8 b_h = *(const s16x8*)(Bh + off);
      s16x8 b_l = *(const s16x8*)(Bl + off);
      #pragma unroll
      for (int i = 0; i < 4; ++i){
        acc[i][j] = __builtin_amdgcn_mfma_f32_16x16x32_bf16(a_h[i], b_h, acc[i][j], 0, 0, 0);
        acc[i][j] = __builtin_amdgcn_mfma_f32_16x16x32_bf16(a_h[i], b_l, acc[i][j], 0, 0, 0);
        acc[i][j] = __builtin_amdgcn_mfma_f32_16x16x32_bf16(a_l[i], b_h, acc[i][j], 0, 0, 0);
      }
    }
  }
  __syncthreads();
  // epilogue: + bc, per-row argmax over this 128-col tile (ties -> lowest index)
  const int g = lane >> 4;
  #pragma unroll
  for (int i = 0; i < 4; ++i){
    #pragma unroll
    for (int r = 0; r < 4; ++r){
      float bv = -__builtin_inff(); int bi = 0x7FFFFFFF;
      #pragma unroll
      for (int j = 0; j < 4; ++j){
        int col = n0 + wq * 64 + j * 16 + (lane & 15);
        if (col < NCLS){
          float v = acc[i][j][r] + bc[col];
          if (v > bv){ bv = v; bi = col; }
        }
      }
      for (int s = 1; s < 16; s <<= 1){
        float ov = __shfl_xor(bv, s);
        int   oi = __shfl_xor(bi, s);
        if (ov > bv || (ov == bv && oi < bi)){ bv = ov; bi = oi; }
      }
      if ((lane & 15) == 0){
        int rloc = wr * 64 + i * 16 + g * 4 + r;
        cmax[rloc * 2 + wq] = bv;
        cidx[rloc * 2 + wq] = bi;
      }
    }
  }
  __syncthreads();
  if (tid < 128){
    float bv = cmax[tid * 2];     int bi = cidx[tid * 2];
    float v1 = cmax[tid * 2 + 1]; int i1 = cidx[tid * 2 + 1];
    if (v1 > bv || (v1 == bv && i1 < bi)){ bv = v1; bi = i1; }
    size_t row = (size_t)(m0 + tid);
    g_pmax[row * NTILE_N + ntile] = bv;
    g_pidx[row * NTILE_N + ntile] = bi;
  }
}

// ---------------- K3: combine tile argmaxes per row, then min over 60 combos ------
__global__ __launch_bounds__(64) void k_best(float* __restrict__ out)
{
  __shared__ int bis[60];
  const int s = blockIdx.x; const int t = threadIdx.x;
  if (t < 60){
    size_t row = (size_t)s * 60 + t;
    float bv = -__builtin_inff(); int bi = 0x7FFFFFFF;
    for (int q = 0; q < NTILE_N; ++q){
      float v = g_pmax[row * NTILE_N + q];
      int   i = g_pidx[row * NTILE_N + q];
      if (v > bv || (v == bv && i < bi)){ bv = v; bi = i; }
    }
    bis[t] = bi;
  }
  __syncthreads();
  if (t == 0){
    int m = bis[0];
    for (int i = 1; i < 60; ++i) m = min(m, bis[i]);
    out[s * 128 + 127] = (float)m;
  }
}

// ---------------- K4: o-head first GEMM via MFMA (bf16), split-K z=30 -------------
__global__ __launch_bounds__(256) void k_o1(void)
{
  __shared__ unsigned char As[16384];
  __shared__ unsigned char Bs[16384];
  const int tid  = threadIdx.x;
  const int lane = tid & 63;
  const int wv   = tid >> 6;
  const int wr   = wv >> 1, wq = wv & 1;
  const int n0  = blockIdx.x * 128;
  const int m0  = blockIdx.y * 128;
  const int kc0 = blockIdx.z * O1_KZ;

  f32x4 acc[4][4];
  #pragma unroll
  for (int i = 0; i < 4; ++i)
    #pragma unroll
    for (int j = 0; j < 4; ++j)
      acc[i][j] = (f32x4){0.f, 0.f, 0.f, 0.f};

  const int rA = lane >> 3;
  const int c0 = lane & 7;
  for (int kk = 0; kk < O1_KZ; kk += 64){
    int kc = kc0 + kk;
    __syncthreads();
    #pragma unroll
    for (int it = 0; it < 4; ++it){
      int seg = wv * 4 + it;
      int r   = seg * 8 + rA;
      int cs  = c0 ^ (r & 7);
      gload16(g_rawbf + (size_t)(m0 + r) * 15360 + kc + cs * 8, As + seg * 1024);
      gload16(g_wo1bf + (size_t)(n0 + r) * 15360 + kc + cs * 8, Bs + seg * 1024);
    }
    __syncthreads();
    #pragma unroll
    for (int ks = 0; ks < 2; ++ks){
      int q = ks * 4 + (lane >> 4);
      s16x8 a[4];
      #pragma unroll
      for (int i = 0; i < 4; ++i){
        int row = wr * 64 + i * 16 + (lane & 15);
        a[i] = *(const s16x8*)(As + row * 128 + ((q ^ (row & 7)) * 16));
      }
      #pragma unroll
      for (int j = 0; j < 4; ++j){
        int col = wq * 64 + j * 16 + (lane & 15);
        s16x8 b = *(const s16x8*)(Bs + col * 128 + ((q ^ (col & 7)) * 16));
        #pragma unroll
        for (int i = 0; i < 4; ++i)
          acc[i][j] = __builtin_amdgcn_mfma_f32_16x16x32_bf16(a[i], b, acc[i][j], 0, 0, 0);
      }
    }
  }
  const int g = lane >> 4;
  #pragma unroll
  for (int i = 0; i < 4; ++i)
    #pragma unroll
    for (int j = 0; j < 4; ++j)
      #pragma unroll
      for (int r = 0; r < 4; ++r){
        int gm = m0 + wr * 64 + i * 16 + g * 4 + r;
        int gn = n0 + wq * 64 + j * 16 + (lane & 15);
        g_part[((size_t)blockIdx.z * NSAMP + gm) * 512 + gn] = acc[i][j][r];
      }
}

// ---------------- K5: o-head tail: reduce split-K, relu, 512->256->127 ------------
__global__ __launch_bounds__(256) void k_otail(
    const float* __restrict__ bo1, const float* __restrict__ wo2,
    const float* __restrict__ bo2, const float* __restrict__ wo3,
    const float* __restrict__ bo3, float* __restrict__ out)
{
  __shared__ float o1f[512];
  __shared__ float o2f[256];
  const int s = blockIdx.x;
  const int tid = threadIdx.x;
  for (int j = tid; j < 512; j += 256){
    float a = bo1[j];
    for (int ks = 0; ks < O1_NZ; ++ks) a += g_part[((size_t)ks * NSAMP + s) * 512 + j];
    o1f[j] = fmaxf(a, 0.f);
  }
  __syncthreads();
  {
    float a = bo2[tid];
    const float* wr = wo2 + (size_t)tid * 512;
    for (int i = 0; i < 512; i += 4){
      float4 w4 = *(const float4*)(wr + i);
      a += o1f[i]*w4.x + o1f[i+1]*w4.y + o1f[i+2]*w4.z + o1f[i+3]*w4.w;
    }
    o2f[tid] = fmaxf(a, 0.f);
  }
  __syncthreads();
  if (tid < 127){
    float a = bo3[tid];
    const float* wr = wo3 + (size_t)tid * 256;
    for (int i = 0; i < 256; i += 4){
      float4 w4 = *(const float4*)(wr + i);
      a += o2f[i]*w4.x + o2f[i+1]*w4.y + o2f[i+2]*w4.z + o2f[i+3]*w4.w;
    }
    out[s * 128 + tid] = fmaxf(a, 0.f);
  }
}

extern "C" void kernel_launch(void* const* d_in, const int* in_sizes, int n_in,
                              void* d_out, int out_size, void* d_ws, size_t ws_size,
                              hipStream_t stream)
{
  (void)d_ws; (void)ws_size; (void)in_sizes; (void)n_in; (void)out_size;
  const int*   x      = (const int*)  d_in[0];
  const float* suit_w = (const float*)d_in[1];
  const float* suit_b = (const float*)d_in[2];
  const float* rank_w = (const float*)d_in[3];
  const float* rank_b = (const float*)d_in[4];
  const float* bns_g  = (const float*)d_in[5];
  const float* bns_b  = (const float*)d_in[6];
  const float* bns_m  = (const float*)d_in[7];
  const float* bns_v  = (const float*)d_in[8];
  const float* bnr_g  = (const float*)d_in[9];
  const float* bnr_b  = (const float*)d_in[10];
  const float* bnr_m  = (const float*)d_in[11];
  const float* bnr_v  = (const float*)d_in[12];
  const float* w1     = (const float*)d_in[13];
  const float* b1     = (const float*)d_in[14];
  const float* w2     = (const float*)d_in[15];
  const float* b2     = (const float*)d_in[16];
  const float* wc     = (const float*)d_in[17];
  const float* bc     = (const float*)d_in[18];
  const float* wo1    = (const float*)d_in[19];
  const float* bo1    = (const float*)d_in[20];
  const float* wo2    = (const float*)d_in[21];
  const float* bo2    = (const float*)d_in[22];
  const float* wo3    = (const float*)d_in[23];
  const float* bo3    = (const float*)d_in[24];
  float* out = (float*)d_out;

  hipLaunchKernelGGL(k_split,  dim3(3840), dim3(256), 0, stream, wc);
  hipLaunchKernelGGL(k_splitw, dim3(7680), dim3(256), 0, stream, wo1);
  hipLaunchKernelGGL(k_features, dim3(5760), dim3(256), 0, stream, x,
                     suit_w, suit_b, rank_w, rank_b,
                     bns_g, bns_b, bns_m, bns_v, bnr_g, bnr_b, bnr_m, bnr_v,
                     w1, b1, w2, b2);
  hipLaunchKernelGGL(k_logits, dim3(NTILE_N * NTILE_M), dim3(256), 0, stream, bc);
  hipLaunchKernelGGL(k_best, dim3(NSAMP), dim3(64), 0, stream, out);
  hipLaunchKernelGGL(k_o1, dim3(4, 3, O1_NZ), dim3(256), 0, stream);
  hipLaunchKernelGGL(k_otail, dim3(NSAMP), dim3(256), 0, stream,
                     bo1, wo2, bo2, wo3, bo3, out);
}

// Round 7
// 1267.563 us; speedup vs baseline: 2.0252x; 1.0492x over previous
//
#include <hip/hip_runtime.h>

#define NSAMP 384
#define NCOMBO 60
#define NROW 23040
#define KDIM 512
#define NCLS 7463
#define NCLSP 7680
#define NTILE_N 60
#define NTILE_M 180
#define BANDM 20
#define O1_NZ 30
#define O1_KZ 512

typedef short s16x8 __attribute__((ext_vector_type(8)));
typedef short s16x4 __attribute__((ext_vector_type(4)));
typedef float f32x4 __attribute__((ext_vector_type(4)));

// ---- module-level scratch (every byte rewritten each call before any read) ----
__device__ unsigned short g_wc_hi[NCLSP * KDIM];
__device__ unsigned short g_wc_lo[NCLSP * KDIM];
__device__ unsigned short g_h_hi[NROW * KDIM];
__device__ unsigned short g_h_lo[NROW * KDIM];
__device__ unsigned short g_rawbf[NROW * 256];          // == [NSAMP][15360]
__device__ unsigned short g_wo1bf[512 * 15360];
__device__ float          g_pmax[NROW * NTILE_N];
__device__ int            g_pidx[NROW * NTILE_N];
__device__ float          g_part[O1_NZ * NSAMP * 512];

__device__ __forceinline__ float bf2f(unsigned short u){
  union { unsigned int i; float f; } v; v.i = ((unsigned int)u) << 16; return v.f;
}
__device__ __forceinline__ unsigned short f2bf(float f){
  union { float f; unsigned int i; } v; v.f = f;
  unsigned int u = v.i;
  unsigned int r = (u + 0x7FFFu + ((u >> 16) & 1u)) >> 16;
  return (unsigned short)r;
}
__device__ __forceinline__ void gload16(const void* g, void* l){
  __builtin_amdgcn_global_load_lds((const __attribute__((address_space(1))) void*)g,
                                   (__attribute__((address_space(3))) void*)l, 16, 0, 0);
}

// ---------------- K0: split wc into bf16 hi/lo, zero-pad to 7680 (vectorized) -----
__global__ __launch_bounds__(256) void k_split(const float* __restrict__ wc)
{
  int idx = (blockIdx.x * 256 + threadIdx.x) * 4;    // grid 3840 -> covers NCLSP*KDIM
  float4 w = {0.f, 0.f, 0.f, 0.f};
  if (idx < NCLS * KDIM) w = *(const float4*)(wc + idx);   // boundary is 4-aligned
  s16x4 hi, lo;
  float wv[4] = {w.x, w.y, w.z, w.w};
  #pragma unroll
  for (int i = 0; i < 4; ++i){
    unsigned short h = f2bf(wv[i]);
    hi[i] = (short)h;
    lo[i] = (short)f2bf(wv[i] - bf2f(h));
  }
  *(s16x4*)(g_wc_hi + idx) = hi;
  *(s16x4*)(g_wc_lo + idx) = lo;
}

// ---------------- K0b: wo1 -> bf16 (vectorized) ----------------
__global__ __launch_bounds__(256) void k_splitw(const float* __restrict__ wo1)
{
  int idx = (blockIdx.x * 256 + threadIdx.x) * 4;    // grid 7680 -> 512*15360 exactly
  float4 w = *(const float4*)(wo1 + idx);
  s16x4 b;
  b[0] = (short)f2bf(w.x); b[1] = (short)f2bf(w.y);
  b[2] = (short)f2bf(w.z); b[3] = (short)f2bf(w.w);
  *(s16x4*)(g_wo1bf + idx) = b;
}

// ---------------- K1: per-combo features -> h hi/lo + raw bf16 ----------------
__global__ __launch_bounds__(256) void k_features(
    const int* __restrict__ x,
    const float* __restrict__ suit_w, const float* __restrict__ suit_b,
    const float* __restrict__ rank_w, const float* __restrict__ rank_b,
    const float* __restrict__ bns_g, const float* __restrict__ bns_b,
    const float* __restrict__ bns_m, const float* __restrict__ bns_v,
    const float* __restrict__ bnr_g, const float* __restrict__ bnr_b,
    const float* __restrict__ bnr_m, const float* __restrict__ bnr_v,
    const float* __restrict__ w1, const float* __restrict__ b1,
    const float* __restrict__ w2, const float* __restrict__ b2)
{
  __shared__ float raw_s[4][256];
  __shared__ float h1_s[4][512];
  const int tid  = threadIdx.x;
  const int lane = tid & 63;
  const int wv   = tid >> 6;
  const int combo = blockIdx.x * 4 + wv;
  const int s = combo / 60;
  const int k = combo % 60;
  const int hp = k / 10, bt = k % 10;
  const int HP0[6]  = {0,0,0,1,1,2}, HP1[6] = {1,2,3,2,3,3};
  const int BT0[10] = {4,4,4,4,4,4,5,5,5,6};
  const int BT1[10] = {5,5,5,6,6,7,6,6,7,7};
  const int BT2[10] = {6,7,8,7,8,8,7,8,8,8};
  int cards[5] = {HP0[hp], HP1[hp], BT0[bt], BT1[bt], BT2[bt]};
  const int* xp = x + s * 18;
  int rk[5], st[5];
  #pragma unroll
  for (int c = 0; c < 5; ++c){ rk[c] = xp[2*cards[c]]; st[c] = xp[2*cards[c] + 1]; }

  // raw features: lane owns 4 consecutive elements -> one 8B store
  {
    s16x4 rv;
    #pragma unroll
    for (int i = 0; i < 4; ++i){
      int e = lane * 4 + i;
      int o = e >> 4, l = e & 15;
      float v;
      if (l < 11){
        float a = 0.f;
        #pragma unroll
        for (int c = 0; c < 5; ++c){
          int d = rk[c] - l;
          if (d >= 0 && d < 5) a += rank_w[o*25 + c*5 + d];
        }
        a += rank_b[o];
        float inv = bnr_g[o] / sqrtf(bnr_v[o] + 1e-5f);
        v = a * inv + (bnr_b[o] - bnr_m[o] * inv);
      } else {
        int j = l - 11;
        float a = suit_b[o];
        #pragma unroll
        for (int c = 0; c < 5; ++c) if (st[c] == j) a += suit_w[o*5 + c];
        float inv = bns_g[o] / sqrtf(bns_v[o] + 1e-5f);
        v = a * inv + (bns_b[o] - bns_m[o] * inv);
      }
      v = fmaxf(v, 0.f);
      raw_s[wv][e] = v;
      rv[i] = (short)f2bf(v);
    }
    *(s16x4*)(g_rawbf + (size_t)s * 15360 + k * 256 + lane * 4) = rv;
  }
  __syncthreads();
  #pragma unroll
  for (int i = 0; i < 8; ++i){
    int e = lane + 64 * i;
    int o = e >> 5, j = e & 31;
    float a = b1[j];
    #pragma unroll
    for (int l = 0; l < 16; ++l) a += raw_s[wv][o*16 + l] * w1[j*16 + l];
    h1_s[wv][e] = fmaxf(a, 0.f);
  }
  __syncthreads();
  // h2: lane owns 8 consecutive elements -> one 16B store per array
  {
    s16x8 hv, lv;
    #pragma unroll
    for (int i = 0; i < 8; ++i){
      int e = lane * 8 + i;
      int o = e >> 5, j = e & 31;
      float a = b2[j];
      #pragma unroll
      for (int l = 0; l < 32; ++l) a += h1_s[wv][o*32 + l] * w2[j*32 + l];
      a = fmaxf(a, 0.f);
      unsigned short h = f2bf(a);
      hv[i] = (short)h;
      lv[i] = (short)f2bf(a - bf2f(h));
    }
    *(s16x8*)(g_h_hi + (size_t)combo * 512 + lane * 8) = hv;
    *(s16x8*)(g_h_lo + (size_t)combo * 512 + lane * 8) = lv;
  }
}

// ---------------- K2: logits GEMM (split-bf16, 3 MFMA) + fused per-tile argmax ----
// 128x128 tile, BK=32 (LDS 32KB -> 4 blocks/CU). Banded schedule: band = 20 m-tiles
// x all 60 n-tiles = 1200 blocks (~ concurrent capacity); within band n fastest so
// 60 consecutive blocks share one A-panel, write contiguous pmax rows (L2 merge),
// and the live working set (A-band 5MB + B 15.7MB) stays L2/L3-resident.
__global__ __launch_bounds__(256, 4) void k_logits(const float* __restrict__ bc)
{
  __shared__ unsigned char Ah[8192];   // [128 rows][64B]
  __shared__ unsigned char Al[8192];
  __shared__ unsigned char Bh[8192];
  __shared__ unsigned char Bl[8192];
  __shared__ float cmax[256];
  __shared__ int   cidx[256];
  const int tid  = threadIdx.x;
  const int lane = tid & 63;
  const int wv   = tid >> 6;
  const int wr   = wv >> 1, wq = wv & 1;
  const int flat  = blockIdx.x;                  // 10800 = 9 bands x 1200
  const int band  = flat / (BANDM * NTILE_N);
  const int local = flat % (BANDM * NTILE_N);
  const int mt    = band * BANDM + local / NTILE_N;
  const int nt    = local % NTILE_N;
  const int m0 = mt * 128;
  const int n0 = nt * 128;

  f32x4 acc[4][4];
  #pragma unroll
  for (int i = 0; i < 4; ++i)
    #pragma unroll
    for (int j = 0; j < 4; ++j)
      acc[i][j] = (f32x4){0.f, 0.f, 0.f, 0.f};

  const int rA = lane >> 2;                 // row within 16-row segment
  const int c0 = lane & 3;                  // dest chunk (16B units)
  for (int kc = 0; kc < KDIM; kc += 32){
    __syncthreads();
    #pragma unroll
    for (int it = 0; it < 2; ++it){
      int seg = wv * 2 + it;                // wave-uniform, 0..7
      int r   = seg * 16 + rA;              // 0..127
      int cs  = c0 ^ ((rA >> 1) & 3);       // pre-swizzled source chunk
      size_t gA = (size_t)(m0 + r) * KDIM + kc + cs * 8;
      size_t gB = (size_t)(n0 + r) * KDIM + kc + cs * 8;
      unsigned lb = seg * 1024;
      gload16(g_h_hi  + gA, Ah + lb);
      gload16(g_h_lo  + gA, Al + lb);
      gload16(g_wc_hi + gB, Bh + lb);
      gload16(g_wc_lo + gB, Bl + lb);
    }
    __syncthreads();
    const int q = lane >> 4;                // 8-elem k-chunk 0..3
    s16x8 a_h[4], a_l[4];
    #pragma unroll
    for (int i = 0; i < 4; ++i){
      int row = wr * 64 + i * 16 + (lane & 15);
      int off = row * 64 + ((q ^ ((row >> 1) & 3)) * 16);
      a_h[i] = *(const s16x8*)(Ah + off);
      a_l[i] = *(const s16x8*)(Al + off);
    }
    #pragma unroll
    for (int j = 0; j < 4; ++j){
      int col = wq * 64 + j * 16 + (lane & 15);
      int off = col * 64 + ((q ^ ((col >> 1) & 3)) * 16);
      s16x8 b_h = *(const s16x8*)(Bh + off);
      s16x8 b_l = *(const s16x8*)(Bl + off);
      #pragma unroll
      for (int i = 0; i < 4; ++i){
        acc[i][j] = __builtin_amdgcn_mfma_f32_16x16x32_bf16(a_h[i], b_h, acc[i][j], 0, 0, 0);
        acc[i][j] = __builtin_amdgcn_mfma_f32_16x16x32_bf16(a_h[i], b_l, acc[i][j], 0, 0, 0);
        acc[i][j] = __builtin_amdgcn_mfma_f32_16x16x32_bf16(a_l[i], b_h, acc[i][j], 0, 0, 0);
      }
    }
  }
  __syncthreads();
  // epilogue: + bc, per-row argmax over this 128-col tile (ties -> lowest index)
  const int g = lane >> 4;
  #pragma unroll
  for (int i = 0; i < 4; ++i){
    #pragma unroll
    for (int r = 0; r < 4; ++r){
      float bv = -__builtin_inff(); int bi = 0x7FFFFFFF;
      #pragma unroll
      for (int j = 0; j < 4; ++j){
        int col = n0 + wq * 64 + j * 16 + (lane & 15);
        if (col < NCLS){
          float v = acc[i][j][r] + bc[col];
          if (v > bv){ bv = v; bi = col; }
        }
      }
      for (int s = 1; s < 16; s <<= 1){
        float ov = __shfl_xor(bv, s);
        int   oi = __shfl_xor(bi, s);
        if (ov > bv || (ov == bv && oi < bi)){ bv = ov; bi = oi; }
      }
      if ((lane & 15) == 0){
        int rloc = wr * 64 + i * 16 + g * 4 + r;
        cmax[rloc * 2 + wq] = bv;
        cidx[rloc * 2 + wq] = bi;
      }
    }
  }
  __syncthreads();
  if (tid < 128){
    float bv = cmax[tid * 2];     int bi = cidx[tid * 2];
    float v1 = cmax[tid * 2 + 1]; int i1 = cidx[tid * 2 + 1];
    if (v1 > bv || (v1 == bv && i1 < bi)){ bv = v1; bi = i1; }
    size_t row = (size_t)(m0 + tid);
    g_pmax[row * NTILE_N + nt] = bv;
    g_pidx[row * NTILE_N + nt] = bi;
  }
}

// ---------------- K3: combine tile argmaxes per row, then min over 60 combos ------
__global__ __launch_bounds__(64) void k_best(float* __restrict__ out)
{
  __shared__ int bis[60];
  const int s = blockIdx.x; const int t = threadIdx.x;
  if (t < 60){
    size_t row = (size_t)s * 60 + t;
    float bv = -__builtin_inff(); int bi = 0x7FFFFFFF;
    for (int q = 0; q < NTILE_N; ++q){
      float v = g_pmax[row * NTILE_N + q];
      int   i = g_pidx[row * NTILE_N + q];
      if (v > bv || (v == bv && i < bi)){ bv = v; bi = i; }
    }
    bis[t] = bi;
  }
  __syncthreads();
  if (t == 0){
    int m = bis[0];
    for (int i = 1; i < 60; ++i) m = min(m, bis[i]);
    out[s * 128 + 127] = (float)m;
  }
}

// ---------------- K4: o-head first GEMM via MFMA (bf16), split-K z=30 -------------
__global__ __launch_bounds__(256) void k_o1(void)
{
  __shared__ unsigned char As[16384];
  __shared__ unsigned char Bs[16384];
  const int tid  = threadIdx.x;
  const int lane = tid & 63;
  const int wv   = tid >> 6;
  const int wr   = wv >> 1, wq = wv & 1;
  const int n0  = blockIdx.x * 128;
  const int m0  = blockIdx.y * 128;
  const int kc0 = blockIdx.z * O1_KZ;

  f32x4 acc[4][4];
  #pragma unroll
  for (int i = 0; i < 4; ++i)
    #pragma unroll
    for (int j = 0; j < 4; ++j)
      acc[i][j] = (f32x4){0.f, 0.f, 0.f, 0.f};

  const int rA = lane >> 3;
  const int c0 = lane & 7;
  for (int kk = 0; kk < O1_KZ; kk += 64){
    int kc = kc0 + kk;
    __syncthreads();
    #pragma unroll
    for (int it = 0; it < 4; ++it){
      int seg = wv * 4 + it;
      int r   = seg * 8 + rA;
      int cs  = c0 ^ (r & 7);
      gload16(g_rawbf + (size_t)(m0 + r) * 15360 + kc + cs * 8, As + seg * 1024);
      gload16(g_wo1bf + (size_t)(n0 + r) * 15360 + kc + cs * 8, Bs + seg * 1024);
    }
    __syncthreads();
    #pragma unroll
    for (int ks = 0; ks < 2; ++ks){
      int q = ks * 4 + (lane >> 4);
      s16x8 a[4];
      #pragma unroll
      for (int i = 0; i < 4; ++i){
        int row = wr * 64 + i * 16 + (lane & 15);
        a[i] = *(const s16x8*)(As + row * 128 + ((q ^ (row & 7)) * 16));
      }
      #pragma unroll
      for (int j = 0; j < 4; ++j){
        int col = wq * 64 + j * 16 + (lane & 15);
        s16x8 b = *(const s16x8*)(Bs + col * 128 + ((q ^ (col & 7)) * 16));
        #pragma unroll
        for (int i = 0; i < 4; ++i)
          acc[i][j] = __builtin_amdgcn_mfma_f32_16x16x32_bf16(a[i], b, acc[i][j], 0, 0, 0);
      }
    }
  }
  const int g = lane >> 4;
  #pragma unroll
  for (int i = 0; i < 4; ++i)
    #pragma unroll
    for (int j = 0; j < 4; ++j)
      #pragma unroll
      for (int r = 0; r < 4; ++r){
        int gm = m0 + wr * 64 + i * 16 + g * 4 + r;
        int gn = n0 + wq * 64 + j * 16 + (lane & 15);
        g_part[((size_t)blockIdx.z * NSAMP + gm) * 512 + gn] = acc[i][j][r];
      }
}

// ---------------- K5: o-head tail: reduce split-K, relu, 512->256->127 ------------
__global__ __launch_bounds__(256) void k_otail(
    const float* __restrict__ bo1, const float* __restrict__ wo2,
    const float* __restrict__ bo2, const float* __restrict__ wo3,
    const float* __restrict__ bo3, float* __restrict__ out)
{
  __shared__ float o1f[512];
  __shared__ float o2f[256];
  const int s = blockIdx.x;
  const int tid = threadIdx.x;
  for (int j = tid; j < 512; j += 256){
    float a = bo1[j];
    for (int ks = 0; ks < O1_NZ; ++ks) a += g_part[((size_t)ks * NSAMP + s) * 512 + j];
    o1f[j] = fmaxf(a, 0.f);
  }
  __syncthreads();
  {
    float a = bo2[tid];
    const float* wr = wo2 + (size_t)tid * 512;
    for (int i = 0; i < 512; i += 4){
      float4 w4 = *(const float4*)(wr + i);
      a += o1f[i]*w4.x + o1f[i+1]*w4.y + o1f[i+2]*w4.z + o1f[i+3]*w4.w;
    }
    o2f[tid] = fmaxf(a, 0.f);
  }
  __syncthreads();
  if (tid < 127){
    float a = bo3[tid];
    const float* wr = wo3 + (size_t)tid * 256;
    for (int i = 0; i < 256; i += 4){
      float4 w4 = *(const float4*)(wr + i);
      a += o2f[i]*w4.x + o2f[i+1]*w4.y + o2f[i+2]*w4.z + o2f[i+3]*w4.w;
    }
    out[s * 128 + tid] = fmaxf(a, 0.f);
  }
}

extern "C" void kernel_launch(void* const* d_in, const int* in_sizes, int n_in,
                              void* d_out, int out_size, void* d_ws, size_t ws_size,
                              hipStream_t stream)
{
  (void)d_ws; (void)ws_size; (void)in_sizes; (void)n_in; (void)out_size;
  const int*   x      = (const int*)  d_in[0];
  const float* suit_w = (const float*)d_in[1];
  const float* suit_b = (const float*)d_in[2];
  const float* rank_w = (const float*)d_in[3];
  const float* rank_b = (const float*)d_in[4];
  const float* bns_g  = (const float*)d_in[5];
  const float* bns_b  = (const float*)d_in[6];
  const float* bns_m  = (const float*)d_in[7];
  const float* bns_v  = (const float*)d_in[8];
  const float* bnr_g  = (const float*)d_in[9];
  const float* bnr_b  = (const float*)d_in[10];
  const float* bnr_m  = (const float*)d_in[11];
  const float* bnr_v  = (const float*)d_in[12];
  const float* w1     = (const float*)d_in[13];
  const float* b1     = (const float*)d_in[14];
  const float* w2     = (const float*)d_in[15];
  const float* b2     = (const float*)d_in[16];
  const float* wc     = (const float*)d_in[17];
  const float* bc     = (const float*)d_in[18];
  const float* wo1    = (const float*)d_in[19];
  const float* bo1    = (const float*)d_in[20];
  const float* wo2    = (const float*)d_in[21];
  const float* bo2    = (const float*)d_in[22];
  const float* wo3    = (const float*)d_in[23];
  const float* bo3    = (const float*)d_in[24];
  float* out = (float*)d_out;

  hipLaunchKernelGGL(k_split,  dim3(3840), dim3(256), 0, stream, wc);
  hipLaunchKernelGGL(k_splitw, dim3(7680), dim3(256), 0, stream, wo1);
  hipLaunchKernelGGL(k_features, dim3(5760), dim3(256), 0, stream, x,
                     suit_w, suit_b, rank_w, rank_b,
                     bns_g, bns_b, bns_m, bns_v, bnr_g, bnr_b, bnr_m, bnr_v,
                     w1, b1, w2, b2);
  hipLaunchKernelGGL(k_logits, dim3(NTILE_N * NTILE_M), dim3(256), 0, stream, bc);
  hipLaunchKernelGGL(k_best, dim3(NSAMP), dim3(64), 0, stream, out);
  hipLaunchKernelGGL(k_o1, dim3(4, 3, O1_NZ), dim3(256), 0, stream);
  hipLaunchKernelGGL(k_otail, dim3(NSAMP), dim3(256), 0, stream,
                     bo1, wo2, bo2, wo3, bo3, out);
}

// Round 8
// 1158.009 us; speedup vs baseline: 2.2168x; 1.0946x over previous
//
#include <hip/hip_runtime.h>

#define NSAMP 384
#define NCOMBO 60
#define NROW 23040
#define KDIM 512
#define NCLS 7463
#define NCLSP 7680
#define NTILE_N 60
#define NTILE_M 180
#define O1_NZ 30
#define O1_KZ 512

typedef short s16x8 __attribute__((ext_vector_type(8)));
typedef short s16x4 __attribute__((ext_vector_type(4)));
typedef float f32x4 __attribute__((ext_vector_type(4)));

// ---- module-level scratch (every byte rewritten each call before any read) ----
__device__ unsigned short g_wc_hi[NCLSP * KDIM];
__device__ unsigned short g_wc_lo[NCLSP * KDIM];
__device__ unsigned short g_h_hi[NROW * KDIM];
__device__ unsigned short g_h_lo[NROW * KDIM];
__device__ unsigned short g_rawbf[NROW * 256];          // == [NSAMP][15360]
__device__ unsigned short g_wo1bf[512 * 15360];
__device__ float          g_pmax[NTILE_N * NROW];       // TRANSPOSED: [nt][row]
__device__ int            g_pidx[NTILE_N * NROW];
__device__ float          g_part[O1_NZ * NSAMP * 512];

__device__ __forceinline__ float bf2f(unsigned short u){
  union { unsigned int i; float f; } v; v.i = ((unsigned int)u) << 16; return v.f;
}
__device__ __forceinline__ unsigned short f2bf(float f){
  union { float f; unsigned int i; } v; v.f = f;
  unsigned int u = v.i;
  unsigned int r = (u + 0x7FFFu + ((u >> 16) & 1u)) >> 16;
  return (unsigned short)r;
}
__device__ __forceinline__ void gload16(const void* g, void* l){
  __builtin_amdgcn_global_load_lds((const __attribute__((address_space(1))) void*)g,
                                   (__attribute__((address_space(3))) void*)l, 16, 0, 0);
}

// ---------------- K0: split wc into bf16 hi/lo, zero-pad to 7680 (vectorized) -----
__global__ __launch_bounds__(256) void k_split(const float* __restrict__ wc)
{
  int idx = (blockIdx.x * 256 + threadIdx.x) * 4;
  float4 w = {0.f, 0.f, 0.f, 0.f};
  if (idx < NCLS * KDIM) w = *(const float4*)(wc + idx);
  s16x4 hi, lo;
  float wv[4] = {w.x, w.y, w.z, w.w};
  #pragma unroll
  for (int i = 0; i < 4; ++i){
    unsigned short h = f2bf(wv[i]);
    hi[i] = (short)h;
    lo[i] = (short)f2bf(wv[i] - bf2f(h));
  }
  *(s16x4*)(g_wc_hi + idx) = hi;
  *(s16x4*)(g_wc_lo + idx) = lo;
}

// ---------------- K0b: wo1 -> bf16 (vectorized) ----------------
__global__ __launch_bounds__(256) void k_splitw(const float* __restrict__ wo1)
{
  int idx = (blockIdx.x * 256 + threadIdx.x) * 4;
  float4 w = *(const float4*)(wo1 + idx);
  s16x4 b;
  b[0] = (short)f2bf(w.x); b[1] = (short)f2bf(w.y);
  b[2] = (short)f2bf(w.z); b[3] = (short)f2bf(w.w);
  *(s16x4*)(g_wo1bf + idx) = b;
}

// ---------------- K1: per-combo features -> h hi/lo + raw bf16 ----------------
__global__ __launch_bounds__(256) void k_features(
    const int* __restrict__ x,
    const float* __restrict__ suit_w, const float* __restrict__ suit_b,
    const float* __restrict__ rank_w, const float* __restrict__ rank_b,
    const float* __restrict__ bns_g, const float* __restrict__ bns_b,
    const float* __restrict__ bns_m, const float* __restrict__ bns_v,
    const float* __restrict__ bnr_g, const float* __restrict__ bnr_b,
    const float* __restrict__ bnr_m, const float* __restrict__ bnr_v,
    const float* __restrict__ w1, const float* __restrict__ b1,
    const float* __restrict__ w2, const float* __restrict__ b2)
{
  __shared__ float raw_s[4][256];
  __shared__ float h1_s[4][512];
  const int tid  = threadIdx.x;
  const int lane = tid & 63;
  const int wv   = tid >> 6;
  const int combo = blockIdx.x * 4 + wv;
  const int s = combo / 60;
  const int k = combo % 60;
  const int hp = k / 10, bt = k % 10;
  const int HP0[6]  = {0,0,0,1,1,2}, HP1[6] = {1,2,3,2,3,3};
  const int BT0[10] = {4,4,4,4,4,4,5,5,5,6};
  const int BT1[10] = {5,5,5,6,6,7,6,6,7,7};
  const int BT2[10] = {6,7,8,7,8,8,7,8,8,8};
  int cards[5] = {HP0[hp], HP1[hp], BT0[bt], BT1[bt], BT2[bt]};
  const int* xp = x + s * 18;
  int rk[5], st[5];
  #pragma unroll
  for (int c = 0; c < 5; ++c){ rk[c] = xp[2*cards[c]]; st[c] = xp[2*cards[c] + 1]; }

  {
    s16x4 rv;
    #pragma unroll
    for (int i = 0; i < 4; ++i){
      int e = lane * 4 + i;
      int o = e >> 4, l = e & 15;
      float v;
      if (l < 11){
        float a = 0.f;
        #pragma unroll
        for (int c = 0; c < 5; ++c){
          int d = rk[c] - l;
          if (d >= 0 && d < 5) a += rank_w[o*25 + c*5 + d];
        }
        a += rank_b[o];
        float inv = bnr_g[o] / sqrtf(bnr_v[o] + 1e-5f);
        v = a * inv + (bnr_b[o] - bnr_m[o] * inv);
      } else {
        int j = l - 11;
        float a = suit_b[o];
        #pragma unroll
        for (int c = 0; c < 5; ++c) if (st[c] == j) a += suit_w[o*5 + c];
        float inv = bns_g[o] / sqrtf(bns_v[o] + 1e-5f);
        v = a * inv + (bns_b[o] - bns_m[o] * inv);
      }
      v = fmaxf(v, 0.f);
      raw_s[wv][e] = v;
      rv[i] = (short)f2bf(v);
    }
    *(s16x4*)(g_rawbf + (size_t)s * 15360 + k * 256 + lane * 4) = rv;
  }
  __syncthreads();
  #pragma unroll
  for (int i = 0; i < 8; ++i){
    int e = lane + 64 * i;
    int o = e >> 5, j = e & 31;
    float a = b1[j];
    #pragma unroll
    for (int l = 0; l < 16; ++l) a += raw_s[wv][o*16 + l] * w1[j*16 + l];
    h1_s[wv][e] = fmaxf(a, 0.f);
  }
  __syncthreads();
  {
    s16x8 hv, lv;
    #pragma unroll
    for (int i = 0; i < 8; ++i){
      int e = lane * 8 + i;
      int o = e >> 5, j = e & 31;
      float a = b2[j];
      #pragma unroll
      for (int l = 0; l < 32; ++l) a += h1_s[wv][o*32 + l] * w2[j*32 + l];
      a = fmaxf(a, 0.f);
      unsigned short h = f2bf(a);
      hv[i] = (short)h;
      lv[i] = (short)f2bf(a - bf2f(h));
    }
    *(s16x8*)(g_h_hi + (size_t)combo * 512 + lane * 8) = hv;
    *(s16x8*)(g_h_lo + (size_t)combo * 512 + lane * 8) = lv;
  }
}

// ---------------- K2: logits GEMM (split-bf16, 3 MFMA) + fused per-tile argmax ----
// 128x128 tile, BK=32 DOUBLE-buffered (64KB LDS, 2 blocks/CU), single barrier per
// K-step with stage(next) issued before compute(cur) (T3-min 2-phase). XCD-aware
// schedule: xcd=blockIdx%8; XCD pair-group g owns nt in [15g,15g+15) (B-slice
// 3.9MB ~ L2-resident); mt strided by parity, nt inner (A-panel reuse x15).
// pmax/pidx TRANSPOSED [nt][row] -> contiguous 512B writes per block.
__global__ __launch_bounds__(256, 2) void k_logits(const float* __restrict__ bc)
{
  __shared__ unsigned char lds[65536];   // [buf][Ah|Al|Bh|Bl][128 rows][32k*2B]
  const int tid  = threadIdx.x;
  const int lane = tid & 63;
  const int wv   = tid >> 6;
  const int wr   = wv >> 1, wq = wv & 1;
  const int flat  = blockIdx.x;                  // 10800
  const int xcd   = flat & 7;
  const int seq   = flat >> 3;                   // 0..1349
  const int group = xcd >> 1;                    // 0..3
  const int par   = xcd & 1;
  const int mt    = (seq / 15) * 2 + par;        // parity-strided 0..179
  const int nt    = group * 15 + (seq % 15);     // group-owned 15 n-tiles
  const int m0 = mt * 128;
  const int n0 = nt * 128;

  f32x4 acc[4][4];
  #pragma unroll
  for (int i = 0; i < 4; ++i)
    #pragma unroll
    for (int j = 0; j < 4; ++j)
      acc[i][j] = (f32x4){0.f, 0.f, 0.f, 0.f};

  const int rA = lane >> 2;                 // row within 16-row segment
  const int c0 = lane & 3;                  // dest chunk (16B units)

  // stage one BK=32 K-slice of all four arrays into buffer b
  auto stage = [&](int b, int kc){
    unsigned base = b * 32768;
    #pragma unroll
    for (int it = 0; it < 2; ++it){
      int seg = wv * 2 + it;                // wave-uniform 0..7
      int r   = seg * 16 + rA;              // 0..127
      int cs  = c0 ^ ((rA >> 1) & 3);       // pre-swizzled source chunk
      size_t gA = (size_t)(m0 + r) * KDIM + kc + cs * 8;
      size_t gB = (size_t)(n0 + r) * KDIM + kc + cs * 8;
      unsigned lb = base + seg * 1024;
      gload16(g_h_hi  + gA, lds + lb);
      gload16(g_h_lo  + gA, lds + lb + 8192);
      gload16(g_wc_hi + gB, lds + lb + 16384);
      gload16(g_wc_lo + gB, lds + lb + 24576);
    }
  };

  int buf = 0;
  stage(0, 0);
  __syncthreads();                           // drain vmcnt(0): buf0 ready
  for (int t = 0; t < 16; ++t){
    if (t < 15) stage(buf ^ 1, (t + 1) * 32);   // issue next-slice loads FIRST
    unsigned base = buf * 32768;
    const int q = lane >> 4;                // 8-elem k-chunk 0..3
    s16x8 a_h[4], a_l[4];
    #pragma unroll
    for (int i = 0; i < 4; ++i){
      int row = wr * 64 + i * 16 + (lane & 15);
      unsigned off = base + row * 64 + ((q ^ ((row >> 1) & 3)) * 16);
      a_h[i] = *(const s16x8*)(lds + off);
      a_l[i] = *(const s16x8*)(lds + off + 8192);
    }
    #pragma unroll
    for (int j = 0; j < 4; ++j){
      int col = wq * 64 + j * 16 + (lane & 15);
      unsigned off = base + col * 64 + ((q ^ ((col >> 1) & 3)) * 16);
      s16x8 b_h = *(const s16x8*)(lds + off + 16384);
      s16x8 b_l = *(const s16x8*)(lds + off + 24576);
      #pragma unroll
      for (int i = 0; i < 4; ++i){
        acc[i][j] = __builtin_amdgcn_mfma_f32_16x16x32_bf16(a_h[i], b_h, acc[i][j], 0, 0, 0);
        acc[i][j] = __builtin_amdgcn_mfma_f32_16x16x32_bf16(a_h[i], b_l, acc[i][j], 0, 0, 0);
        acc[i][j] = __builtin_amdgcn_mfma_f32_16x16x32_bf16(a_l[i], b_h, acc[i][j], 0, 0, 0);
      }
    }
    __syncthreads();                         // drains vmcnt+lgkm: next buf ready
    buf ^= 1;
  }
  // epilogue: + bc, per-row argmax over this 128-col tile (ties -> lowest index)
  float* cmax = (float*)lds;                 // [128][2]
  int*   cidx = (int*)(lds + 1024);
  const int g = lane >> 4;
  #pragma unroll
  for (int i = 0; i < 4; ++i){
    #pragma unroll
    for (int r = 0; r < 4; ++r){
      float bv = -__builtin_inff(); int bi = 0x7FFFFFFF;
      #pragma unroll
      for (int j = 0; j < 4; ++j){
        int col = n0 + wq * 64 + j * 16 + (lane & 15);
        if (col < NCLS){
          float v = acc[i][j][r] + bc[col];
          if (v > bv){ bv = v; bi = col; }
        }
      }
      for (int s = 1; s < 16; s <<= 1){
        float ov = __shfl_xor(bv, s);
        int   oi = __shfl_xor(bi, s);
        if (ov > bv || (ov == bv && oi < bi)){ bv = ov; bi = oi; }
      }
      if ((lane & 15) == 0){
        int rloc = wr * 64 + i * 16 + g * 4 + r;
        cmax[rloc * 2 + wq] = bv;
        cidx[rloc * 2 + wq] = bi;
      }
    }
  }
  __syncthreads();
  if (tid < 128){
    float bv = cmax[tid * 2];     int bi = cidx[tid * 2];
    float v1 = cmax[tid * 2 + 1]; int i1 = cidx[tid * 2 + 1];
    if (v1 > bv || (v1 == bv && i1 < bi)){ bv = v1; bi = i1; }
    size_t row = (size_t)(m0 + tid);
    g_pmax[(size_t)nt * NROW + row] = bv;    // contiguous 512B per block
    g_pidx[(size_t)nt * NROW + row] = bi;
  }
}

// ---------------- K3: combine tile argmaxes per row, then min over 60 combos ------
__global__ __launch_bounds__(64) void k_best(float* __restrict__ out)
{
  __shared__ int bis[60];
  const int s = blockIdx.x; const int t = threadIdx.x;
  if (t < 60){
    size_t row = (size_t)s * 60 + t;
    float bv = -__builtin_inff(); int bi = 0x7FFFFFFF;
    for (int q = 0; q < NTILE_N; ++q){
      float v = g_pmax[(size_t)q * NROW + row];
      int   i = g_pidx[(size_t)q * NROW + row];
      if (v > bv || (v == bv && i < bi)){ bv = v; bi = i; }
    }
    bis[t] = bi;
  }
  __syncthreads();
  if (t == 0){
    int m = bis[0];
    for (int i = 1; i < 60; ++i) m = min(m, bis[i]);
    out[s * 128 + 127] = (float)m;
  }
}

// ---------------- K4: o-head first GEMM via MFMA (bf16), split-K z=30 -------------
__global__ __launch_bounds__(256) void k_o1(void)
{
  __shared__ unsigned char As[16384];
  __shared__ unsigned char Bs[16384];
  const int tid  = threadIdx.x;
  const int lane = tid & 63;
  const int wv   = tid >> 6;
  const int wr   = wv >> 1, wq = wv & 1;
  const int n0  = blockIdx.x * 128;
  const int m0  = blockIdx.y * 128;
  const int kc0 = blockIdx.z * O1_KZ;

  f32x4 acc[4][4];
  #pragma unroll
  for (int i = 0; i < 4; ++i)
    #pragma unroll
    for (int j = 0; j < 4; ++j)
      acc[i][j] = (f32x4){0.f, 0.f, 0.f, 0.f};

  const int rA = lane >> 3;
  const int c0 = lane & 7;
  for (int kk = 0; kk < O1_KZ; kk += 64){
    int kc = kc0 + kk;
    __syncthreads();
    #pragma unroll
    for (int it = 0; it < 4; ++it){
      int seg = wv * 4 + it;
      int r   = seg * 8 + rA;
      int cs  = c0 ^ (r & 7);
      gload16(g_rawbf + (size_t)(m0 + r) * 15360 + kc + cs * 8, As + seg * 1024);
      gload16(g_wo1bf + (size_t)(n0 + r) * 15360 + kc + cs * 8, Bs + seg * 1024);
    }
    __syncthreads();
    #pragma unroll
    for (int ks = 0; ks < 2; ++ks){
      int q = ks * 4 + (lane >> 4);
      s16x8 a[4];
      #pragma unroll
      for (int i = 0; i < 4; ++i){
        int row = wr * 64 + i * 16 + (lane & 15);
        a[i] = *(const s16x8*)(As + row * 128 + ((q ^ (row & 7)) * 16));
      }
      #pragma unroll
      for (int j = 0; j < 4; ++j){
        int col = wq * 64 + j * 16 + (lane & 15);
        s16x8 b = *(const s16x8*)(Bs + col * 128 + ((q ^ (col & 7)) * 16));
        #pragma unroll
        for (int i = 0; i < 4; ++i)
          acc[i][j] = __builtin_amdgcn_mfma_f32_16x16x32_bf16(a[i], b, acc[i][j], 0, 0, 0);
      }
    }
  }
  const int g = lane >> 4;
  #pragma unroll
  for (int i = 0; i < 4; ++i)
    #pragma unroll
    for (int j = 0; j < 4; ++j)
      #pragma unroll
      for (int r = 0; r < 4; ++r){
        int gm = m0 + wr * 64 + i * 16 + g * 4 + r;
        int gn = n0 + wq * 64 + j * 16 + (lane & 15);
        g_part[((size_t)blockIdx.z * NSAMP + gm) * 512 + gn] = acc[i][j][r];
      }
}

// ---------------- K5: o-head tail: reduce split-K, relu, 512->256->127 ------------
__global__ __launch_bounds__(256) void k_otail(
    const float* __restrict__ bo1, const float* __restrict__ wo2,
    const float* __restrict__ bo2, const float* __restrict__ wo3,
    const float* __restrict__ bo3, float* __restrict__ out)
{
  __shared__ float o1f[512];
  __shared__ float o2f[256];
  const int s = blockIdx.x;
  const int tid = threadIdx.x;
  for (int j = tid; j < 512; j += 256){
    float a = bo1[j];
    for (int ks = 0; ks < O1_NZ; ++ks) a += g_part[((size_t)ks * NSAMP + s) * 512 + j];
    o1f[j] = fmaxf(a, 0.f);
  }
  __syncthreads();
  {
    float a = bo2[tid];
    const float* wr = wo2 + (size_t)tid * 512;
    for (int i = 0; i < 512; i += 4){
      float4 w4 = *(const float4*)(wr + i);
      a += o1f[i]*w4.x + o1f[i+1]*w4.y + o1f[i+2]*w4.z + o1f[i+3]*w4.w;
    }
    o2f[tid] = fmaxf(a, 0.f);
  }
  __syncthreads();
  if (tid < 127){
    float a = bo3[tid];
    const float* wr = wo3 + (size_t)tid * 256;
    for (int i = 0; i < 256; i += 4){
      float4 w4 = *(const float4*)(wr + i);
      a += o2f[i]*w4.x + o2f[i+1]*w4.y + o2f[i+2]*w4.z + o2f[i+3]*w4.w;
    }
    out[s * 128 + tid] = fmaxf(a, 0.f);
  }
}

extern "C" void kernel_launch(void* const* d_in, const int* in_sizes, int n_in,
                              void* d_out, int out_size, void* d_ws, size_t ws_size,
                              hipStream_t stream)
{
  (void)d_ws; (void)ws_size; (void)in_sizes; (void)n_in; (void)out_size;
  const int*   x      = (const int*)  d_in[0];
  const float* suit_w = (const float*)d_in[1];
  const float* suit_b = (const float*)d_in[2];
  const float* rank_w = (const float*)d_in[3];
  const float* rank_b = (const float*)d_in[4];
  const float* bns_g  = (const float*)d_in[5];
  const float* bns_b  = (const float*)d_in[6];
  const float* bns_m  = (const float*)d_in[7];
  const float* bns_v  = (const float*)d_in[8];
  const float* bnr_g  = (const float*)d_in[9];
  const float* bnr_b  = (const float*)d_in[10];
  const float* bnr_m  = (const float*)d_in[11];
  const float* bnr_v  = (const float*)d_in[12];
  const float* w1     = (const float*)d_in[13];
  const float* b1     = (const float*)d_in[14];
  const float* w2     = (const float*)d_in[15];
  const float* b2     = (const float*)d_in[16];
  const float* wc     = (const float*)d_in[17];
  const float* bc     = (const float*)d_in[18];
  const float* wo1    = (const float*)d_in[19];
  const float* bo1    = (const float*)d_in[20];
  const float* wo2    = (const float*)d_in[21];
  const float* bo2    = (const float*)d_in[22];
  const float* wo3    = (const float*)d_in[23];
  const float* bo3    = (const float*)d_in[24];
  float* out = (float*)d_out;

  hipLaunchKernelGGL(k_split,  dim3(3840), dim3(256), 0, stream, wc);
  hipLaunchKernelGGL(k_splitw, dim3(7680), dim3(256), 0, stream, wo1);
  hipLaunchKernelGGL(k_features, dim3(5760), dim3(256), 0, stream, x,
                     suit_w, suit_b, rank_w, rank_b,
                     bns_g, bns_b, bns_m, bns_v, bnr_g, bnr_b, bnr_m, bnr_v,
                     w1, b1, w2, b2);
  hipLaunchKernelGGL(k_logits, dim3(NTILE_N * NTILE_M), dim3(256), 0, stream, bc);
  hipLaunchKernelGGL(k_best, dim3(NSAMP), dim3(64), 0, stream, out);
  hipLaunchKernelGGL(k_o1, dim3(4, 3, O1_NZ), dim3(256), 0, stream);
  hipLaunchKernelGGL(k_otail, dim3(NSAMP), dim3(256), 0, stream,
                     bo1, wo2, bo2, wo3, bo3, out);
}

// Round 9
// 1155.843 us; speedup vs baseline: 2.2210x; 1.0019x over previous
//
#include <hip/hip_runtime.h>

#define NSAMP 384
#define NCOMBO 60
#define NROW 23040
#define KDIM 512
#define NCLS 7463
#define NCLSP 7680
#define NTILE_N 30
#define NTILE_M 90
#define O1_NZ 30
#define O1_KZ 512

typedef short s16x8 __attribute__((ext_vector_type(8)));
typedef short s16x4 __attribute__((ext_vector_type(4)));
typedef float f32x4 __attribute__((ext_vector_type(4)));

// ---- module-level scratch (every byte rewritten each call before any read) ----
__device__ unsigned short g_wc_hi[NCLSP * KDIM];
__device__ unsigned short g_wc_lo[NCLSP * KDIM];
__device__ unsigned short g_h_hi[NROW * KDIM];
__device__ unsigned short g_h_lo[NROW * KDIM];
__device__ unsigned short g_rawbf[NROW * 256];          // == [NSAMP][15360]
__device__ unsigned short g_wo1bf[512 * 15360];
__device__ float          g_pmax[NTILE_N * NROW];       // [nt][row]
__device__ int            g_pidx[NTILE_N * NROW];
__device__ float          g_part[O1_NZ * NSAMP * 512];

__device__ __forceinline__ float bf2f(unsigned short u){
  union { unsigned int i; float f; } v; v.i = ((unsigned int)u) << 16; return v.f;
}
__device__ __forceinline__ unsigned short f2bf(float f){
  union { float f; unsigned int i; } v; v.f = f;
  unsigned int u = v.i;
  unsigned int r = (u + 0x7FFFu + ((u >> 16) & 1u)) >> 16;
  return (unsigned short)r;
}
__device__ __forceinline__ void gload16(const void* g, void* l){
  __builtin_amdgcn_global_load_lds((const __attribute__((address_space(1))) void*)g,
                                   (__attribute__((address_space(3))) void*)l, 16, 0, 0);
}

// ---------------- K0: split wc into bf16 hi/lo, zero-pad to 7680 (vectorized) -----
__global__ __launch_bounds__(256) void k_split(const float* __restrict__ wc)
{
  int idx = (blockIdx.x * 256 + threadIdx.x) * 4;
  float4 w = {0.f, 0.f, 0.f, 0.f};
  if (idx < NCLS * KDIM) w = *(const float4*)(wc + idx);
  s16x4 hi, lo;
  float wv[4] = {w.x, w.y, w.z, w.w};
  #pragma unroll
  for (int i = 0; i < 4; ++i){
    unsigned short h = f2bf(wv[i]);
    hi[i] = (short)h;
    lo[i] = (short)f2bf(wv[i] - bf2f(h));
  }
  *(s16x4*)(g_wc_hi + idx) = hi;
  *(s16x4*)(g_wc_lo + idx) = lo;
}

// ---------------- K0b: wo1 -> bf16 (vectorized) ----------------
__global__ __launch_bounds__(256) void k_splitw(const float* __restrict__ wo1)
{
  int idx = (blockIdx.x * 256 + threadIdx.x) * 4;
  float4 w = *(const float4*)(wo1 + idx);
  s16x4 b;
  b[0] = (short)f2bf(w.x); b[1] = (short)f2bf(w.y);
  b[2] = (short)f2bf(w.z); b[3] = (short)f2bf(w.w);
  *(s16x4*)(g_wo1bf + idx) = b;
}

// ---------------- K1: per-combo features -> h hi/lo + raw bf16 ----------------
__global__ __launch_bounds__(256) void k_features(
    const int* __restrict__ x,
    const float* __restrict__ suit_w, const float* __restrict__ suit_b,
    const float* __restrict__ rank_w, const float* __restrict__ rank_b,
    const float* __restrict__ bns_g, const float* __restrict__ bns_b,
    const float* __restrict__ bns_m, const float* __restrict__ bns_v,
    const float* __restrict__ bnr_g, const float* __restrict__ bnr_b,
    const float* __restrict__ bnr_m, const float* __restrict__ bnr_v,
    const float* __restrict__ w1, const float* __restrict__ b1,
    const float* __restrict__ w2, const float* __restrict__ b2)
{
  __shared__ float raw_s[4][256];
  __shared__ float h1_s[4][512];
  const int tid  = threadIdx.x;
  const int lane = tid & 63;
  const int wv   = tid >> 6;
  const int combo = blockIdx.x * 4 + wv;
  const int s = combo / 60;
  const int k = combo % 60;
  const int hp = k / 10, bt = k % 10;
  const int HP0[6]  = {0,0,0,1,1,2}, HP1[6] = {1,2,3,2,3,3};
  const int BT0[10] = {4,4,4,4,4,4,5,5,5,6};
  const int BT1[10] = {5,5,5,6,6,7,6,6,7,7};
  const int BT2[10] = {6,7,8,7,8,8,7,8,8,8};
  int cards[5] = {HP0[hp], HP1[hp], BT0[bt], BT1[bt], BT2[bt]};
  const int* xp = x + s * 18;
  int rk[5], st[5];
  #pragma unroll
  for (int c = 0; c < 5; ++c){ rk[c] = xp[2*cards[c]]; st[c] = xp[2*cards[c] + 1]; }

  {
    s16x4 rv;
    #pragma unroll
    for (int i = 0; i < 4; ++i){
      int e = lane * 4 + i;
      int o = e >> 4, l = e & 15;
      float v;
      if (l < 11){
        float a = 0.f;
        #pragma unroll
        for (int c = 0; c < 5; ++c){
          int d = rk[c] - l;
          if (d >= 0 && d < 5) a += rank_w[o*25 + c*5 + d];
        }
        a += rank_b[o];
        float inv = bnr_g[o] / sqrtf(bnr_v[o] + 1e-5f);
        v = a * inv + (bnr_b[o] - bnr_m[o] * inv);
      } else {
        int j = l - 11;
        float a = suit_b[o];
        #pragma unroll
        for (int c = 0; c < 5; ++c) if (st[c] == j) a += suit_w[o*5 + c];
        float inv = bns_g[o] / sqrtf(bns_v[o] + 1e-5f);
        v = a * inv + (bns_b[o] - bns_m[o] * inv);
      }
      v = fmaxf(v, 0.f);
      raw_s[wv][e] = v;
      rv[i] = (short)f2bf(v);
    }
    *(s16x4*)(g_rawbf + (size_t)s * 15360 + k * 256 + lane * 4) = rv;
  }
  __syncthreads();
  #pragma unroll
  for (int i = 0; i < 8; ++i){
    int e = lane + 64 * i;
    int o = e >> 5, j = e & 31;
    float a = b1[j];
    #pragma unroll
    for (int l = 0; l < 16; ++l) a += raw_s[wv][o*16 + l] * w1[j*16 + l];
    h1_s[wv][e] = fmaxf(a, 0.f);
  }
  __syncthreads();
  {
    s16x8 hv, lv;
    #pragma unroll
    for (int i = 0; i < 8; ++i){
      int e = lane * 8 + i;
      int o = e >> 5, j = e & 31;
      float a = b2[j];
      #pragma unroll
      for (int l = 0; l < 32; ++l) a += h1_s[wv][o*32 + l] * w2[j*32 + l];
      a = fmaxf(a, 0.f);
      unsigned short h = f2bf(a);
      hv[i] = (short)h;
      lv[i] = (short)f2bf(a - bf2f(h));
    }
    *(s16x8*)(g_h_hi + (size_t)combo * 512 + lane * 8) = hv;
    *(s16x8*)(g_h_lo + (size_t)combo * 512 + lane * 8) = lv;
  }
}

// ---------------- K2: logits GEMM, virtual-K split + counted-vmcnt pipeline -------
// C = [ah|ah|al] . [bh|bl|bh]^T over virtual K = 1536 (exactly the 3-term split).
// BM=BN=256, BK=32, 8 waves (2M x 4N), per-wave 128x64 out. LDS 2 x 32KB dbuf.
// Per K-tile: ds_read(cur)+MFMA; s_barrier; stage(cur, t+2); s_waitcnt vmcnt(4)
// [tile t+1 confirmed, t+2's 4 loads stay IN FLIGHT]; s_barrier. Never vmcnt(0)
// in the loop (T3+T4). Read swizzle chunk^=(row>>1)&3 (2-way, free); staged via
// inverse-swizzled global source (both-sides rule).
__global__ __launch_bounds__(512, 2) void k_logits(const float* __restrict__ bc)
{
  __shared__ unsigned char lds[65536];
  const int tid  = threadIdx.x;
  const int lane = tid & 63;
  const int wv   = tid >> 6;                 // 0..7
  const int wm   = wv >> 2, wn = wv & 3;     // 2M x 4N
  const int blk  = blockIdx.x;               // 2700 = 30 nt x 90 mt, m-fastest
  const int nt   = blk / NTILE_M;
  const int mt   = blk % NTILE_M;
  const int m0 = mt * 256;
  const int n0 = nt * 256;

  f32x4 acc[8][4];
  #pragma unroll
  for (int i = 0; i < 8; ++i)
    #pragma unroll
    for (int j = 0; j < 4; ++j)
      acc[i][j] = (f32x4){0.f, 0.f, 0.f, 0.f};

  // staging: per K-tile stage A (256x64B=16KB, 2 insts) + B (16KB, 2 insts).
  // dest linear: inst it, thread t -> byte it*8192 + t*16 (wave-uniform base+lane*16)
  const int sR0 = tid >> 2;                  // base row within 128-row half
  const int sCS = (tid & 3) ^ ((tid >> 3) & 3);   // inverse-swizzled source chunk
  auto stage = [&](int buf, int t){
    const int seg = t >> 4;                  // 16 tiles per 512-K segment
    const int kc  = (t & 15) * 32;
    const unsigned short* As = (seg < 2) ? g_h_hi : g_h_lo;
    const unsigned short* Bs = (seg == 1) ? g_wc_lo : g_wc_hi;
    const unsigned base = buf * 32768;
    #pragma unroll
    for (int it = 0; it < 2; ++it){
      int R = it * 128 + sR0;
      gload16(As + (size_t)(m0 + R) * KDIM + kc + sCS * 8,
              lds + base + it * 8192 + wv * 1024);
    }
    #pragma unroll
    for (int it = 0; it < 2; ++it){
      int R = it * 128 + sR0;
      gload16(Bs + (size_t)(n0 + R) * KDIM + kc + sCS * 8,
              lds + base + 16384 + it * 8192 + wv * 1024);
    }
  };

  stage(0, 0);
  stage(1, 1);
  asm volatile("s_waitcnt vmcnt(4)" ::: "memory");   // tile0's 4 loads done
  __builtin_amdgcn_sched_barrier(0);
  __builtin_amdgcn_s_barrier();
  asm volatile("" ::: "memory");

  const int q = lane >> 4;                   // 16B k-chunk 0..3
  #pragma unroll 1
  for (int t = 0; t < 48; ++t){
    const unsigned cb = (unsigned)(t & 1) * 32768;
    s16x8 af[8], bf[4];
    #pragma unroll
    for (int i = 0; i < 8; ++i){
      int row = wm * 128 + i * 16 + (lane & 15);
      af[i] = *(const s16x8*)(lds + cb + row * 64 + ((q ^ ((row >> 1) & 3)) << 4));
    }
    #pragma unroll
    for (int j = 0; j < 4; ++j){
      int row = wn * 64 + j * 16 + (lane & 15);
      bf[j] = *(const s16x8*)(lds + cb + 16384 + row * 64 + ((q ^ ((row >> 1) & 3)) << 4));
    }
    __builtin_amdgcn_s_setprio(1);
    #pragma unroll
    for (int i = 0; i < 8; ++i)
      #pragma unroll
      for (int j = 0; j < 4; ++j)
        acc[i][j] = __builtin_amdgcn_mfma_f32_16x16x32_bf16(af[i], bf[j], acc[i][j], 0, 0, 0);
    __builtin_amdgcn_s_setprio(0);
    __builtin_amdgcn_sched_barrier(0);
    __builtin_amdgcn_s_barrier();            // all waves done reading buffer cb
    asm volatile("" ::: "memory");
    if (t + 2 < 48){
      stage(t & 1, t + 2);                   // overwrite cb; loads fly across barriers
      asm volatile("s_waitcnt vmcnt(4)" ::: "memory");  // tile t+1 confirmed
    } else {
      asm volatile("s_waitcnt vmcnt(0)" ::: "memory");  // tail drain
    }
    __builtin_amdgcn_sched_barrier(0);
    __builtin_amdgcn_s_barrier();
    asm volatile("" ::: "memory");
  }

  // epilogue: + bc, per-row argmax over this 256-col tile (ties -> lowest index)
  float* cmax = (float*)lds;                 // [256 rows][4 wn]
  int*   cidx = (int*)(lds + 4096);
  const int g = lane >> 4;
  #pragma unroll
  for (int i = 0; i < 8; ++i){
    #pragma unroll
    for (int r = 0; r < 4; ++r){
      float bv = -__builtin_inff(); int bi = 0x7FFFFFFF;
      #pragma unroll
      for (int j = 0; j < 4; ++j){
        int col = n0 + wn * 64 + j * 16 + (lane & 15);
        if (col < NCLS){
          float v = acc[i][j][r] + bc[col];
          if (v > bv){ bv = v; bi = col; }
        }
      }
      for (int s = 1; s < 16; s <<= 1){
        float ov = __shfl_xor(bv, s);
        int   oi = __shfl_xor(bi, s);
        if (ov > bv || (ov == bv && oi < bi)){ bv = ov; bi = oi; }
      }
      if ((lane & 15) == 0){
        int rloc = wm * 128 + i * 16 + g * 4 + r;
        cmax[rloc * 4 + wn] = bv;
        cidx[rloc * 4 + wn] = bi;
      }
    }
  }
  __syncthreads();
  if (tid < 256){
    float bv = cmax[tid * 4]; int bi = cidx[tid * 4];
    #pragma unroll
    for (int wq = 1; wq < 4; ++wq){
      float v = cmax[tid * 4 + wq]; int i1 = cidx[tid * 4 + wq];
      if (v > bv || (v == bv && i1 < bi)){ bv = v; bi = i1; }
    }
    size_t row = (size_t)(m0 + tid);
    g_pmax[(size_t)nt * NROW + row] = bv;
    g_pidx[(size_t)nt * NROW + row] = bi;
  }
}

// ---------------- K3: combine tile argmaxes per row, then min over 60 combos ------
__global__ __launch_bounds__(64) void k_best(float* __restrict__ out)
{
  __shared__ int bis[60];
  const int s = blockIdx.x; const int t = threadIdx.x;
  if (t < 60){
    size_t row = (size_t)s * 60 + t;
    float bv = -__builtin_inff(); int bi = 0x7FFFFFFF;
    for (int q = 0; q < NTILE_N; ++q){
      float v = g_pmax[(size_t)q * NROW + row];
      int   i = g_pidx[(size_t)q * NROW + row];
      if (v > bv || (v == bv && i < bi)){ bv = v; bi = i; }
    }
    bis[t] = bi;
  }
  __syncthreads();
  if (t == 0){
    int m = bis[0];
    for (int i = 1; i < 60; ++i) m = min(m, bis[i]);
    out[s * 128 + 127] = (float)m;
  }
}

// ---------------- K4: o-head first GEMM via MFMA (bf16), split-K z=30 -------------
__global__ __launch_bounds__(256) void k_o1(void)
{
  __shared__ unsigned char As[16384];
  __shared__ unsigned char Bs[16384];
  const int tid  = threadIdx.x;
  const int lane = tid & 63;
  const int wv   = tid >> 6;
  const int wr   = wv >> 1, wq = wv & 1;
  const int n0  = blockIdx.x * 128;
  const int m0  = blockIdx.y * 128;
  const int kc0 = blockIdx.z * O1_KZ;

  f32x4 acc[4][4];
  #pragma unroll
  for (int i = 0; i < 4; ++i)
    #pragma unroll
    for (int j = 0; j < 4; ++j)
      acc[i][j] = (f32x4){0.f, 0.f, 0.f, 0.f};

  const int rA = lane >> 3;
  const int c0 = lane & 7;
  for (int kk = 0; kk < O1_KZ; kk += 64){
    int kc = kc0 + kk;
    __syncthreads();
    #pragma unroll
    for (int it = 0; it < 4; ++it){
      int seg = wv * 4 + it;
      int r   = seg * 8 + rA;
      int cs  = c0 ^ (r & 7);
      gload16(g_rawbf + (size_t)(m0 + r) * 15360 + kc + cs * 8, As + seg * 1024);
      gload16(g_wo1bf + (size_t)(n0 + r) * 15360 + kc + cs * 8, Bs + seg * 1024);
    }
    __syncthreads();
    #pragma unroll
    for (int ks = 0; ks < 2; ++ks){
      int q = ks * 4 + (lane >> 4);
      s16x8 a[4];
      #pragma unroll
      for (int i = 0; i < 4; ++i){
        int row = wr * 64 + i * 16 + (lane & 15);
        a[i] = *(const s16x8*)(As + row * 128 + ((q ^ (row & 7)) * 16));
      }
      #pragma unroll
      for (int j = 0; j < 4; ++j){
        int col = wq * 64 + j * 16 + (lane & 15);
        s16x8 b = *(const s16x8*)(Bs + col * 128 + ((q ^ (col & 7)) * 16));
        #pragma unroll
        for (int i = 0; i < 4; ++i)
          acc[i][j] = __builtin_amdgcn_mfma_f32_16x16x32_bf16(a[i], b, acc[i][j], 0, 0, 0);
      }
    }
  }
  const int g = lane >> 4;
  #pragma unroll
  for (int i = 0; i < 4; ++i)
    #pragma unroll
    for (int j = 0; j < 4; ++j)
      #pragma unroll
      for (int r = 0; r < 4; ++r){
        int gm = m0 + wr * 64 + i * 16 + g * 4 + r;
        int gn = n0 + wq * 64 + j * 16 + (lane & 15);
        g_part[((size_t)blockIdx.z * NSAMP + gm) * 512 + gn] = acc[i][j][r];
      }
}

// ---------------- K5: o-head tail: reduce split-K, relu, 512->256->127 ------------
__global__ __launch_bounds__(256) void k_otail(
    const float* __restrict__ bo1, const float* __restrict__ wo2,
    const float* __restrict__ bo2, const float* __restrict__ wo3,
    const float* __restrict__ bo3, float* __restrict__ out)
{
  __shared__ float o1f[512];
  __shared__ float o2f[256];
  const int s = blockIdx.x;
  const int tid = threadIdx.x;
  for (int j = tid; j < 512; j += 256){
    float a = bo1[j];
    for (int ks = 0; ks < O1_NZ; ++ks) a += g_part[((size_t)ks * NSAMP + s) * 512 + j];
    o1f[j] = fmaxf(a, 0.f);
  }
  __syncthreads();
  {
    float a = bo2[tid];
    const float* wr = wo2 + (size_t)tid * 512;
    for (int i = 0; i < 512; i += 4){
      float4 w4 = *(const float4*)(wr + i);
      a += o1f[i]*w4.x + o1f[i+1]*w4.y + o1f[i+2]*w4.z + o1f[i+3]*w4.w;
    }
    o2f[tid] = fmaxf(a, 0.f);
  }
  __syncthreads();
  if (tid < 127){
    float a = bo3[tid];
    const float* wr = wo3 + (size_t)tid * 256;
    for (int i = 0; i < 256; i += 4){
      float4 w4 = *(const float4*)(wr + i);
      a += o2f[i]*w4.x + o2f[i+1]*w4.y + o2f[i+2]*w4.z + o2f[i+3]*w4.w;
    }
    out[s * 128 + tid] = fmaxf(a, 0.f);
  }
}

extern "C" void kernel_launch(void* const* d_in, const int* in_sizes, int n_in,
                              void* d_out, int out_size, void* d_ws, size_t ws_size,
                              hipStream_t stream)
{
  (void)d_ws; (void)ws_size; (void)in_sizes; (void)n_in; (void)out_size;
  const int*   x      = (const int*)  d_in[0];
  const float* suit_w = (const float*)d_in[1];
  const float* suit_b = (const float*)d_in[2];
  const float* rank_w = (const float*)d_in[3];
  const float* rank_b = (const float*)d_in[4];
  const float* bns_g  = (const float*)d_in[5];
  const float* bns_b  = (const float*)d_in[6];
  const float* bns_m  = (const float*)d_in[7];
  const float* bns_v  = (const float*)d_in[8];
  const float* bnr_g  = (const float*)d_in[9];
  const float* bnr_b  = (const float*)d_in[10];
  const float* bnr_m  = (const float*)d_in[11];
  const float* bnr_v  = (const float*)d_in[12];
  const float* w1     = (const float*)d_in[13];
  const float* b1     = (const float*)d_in[14];
  const float* w2     = (const float*)d_in[15];
  const float* b2     = (const float*)d_in[16];
  const float* wc     = (const float*)d_in[17];
  const float* bc     = (const float*)d_in[18];
  const float* wo1    = (const float*)d_in[19];
  const float* bo1    = (const float*)d_in[20];
  const float* wo2    = (const float*)d_in[21];
  const float* bo2    = (const float*)d_in[22];
  const float* wo3    = (const float*)d_in[23];
  const float* bo3    = (const float*)d_in[24];
  float* out = (float*)d_out;

  hipLaunchKernelGGL(k_split,  dim3(3840), dim3(256), 0, stream, wc);
  hipLaunchKernelGGL(k_splitw, dim3(7680), dim3(256), 0, stream, wo1);
  hipLaunchKernelGGL(k_features, dim3(5760), dim3(256), 0, stream, x,
                     suit_w, suit_b, rank_w, rank_b,
                     bns_g, bns_b, bns_m, bns_v, bnr_g, bnr_b, bnr_m, bnr_v,
                     w1, b1, w2, b2);
  hipLaunchKernelGGL(k_logits, dim3(NTILE_N * NTILE_M), dim3(512), 0, stream, bc);
  hipLaunchKernelGGL(k_best, dim3(NSAMP), dim3(64), 0, stream, out);
  hipLaunchKernelGGL(k_o1, dim3(4, 3, O1_NZ), dim3(256), 0, stream);
  hipLaunchKernelGGL(k_otail, dim3(NSAMP), dim3(256), 0, stream,
                     bo1, wo2, bo2, wo3, bo3, out);
}

// Round 10
// 1082.542 us; speedup vs baseline: 2.3714x; 1.0677x over previous
//
#include <hip/hip_runtime.h>

#define NSAMP 384
#define NCOMBO 60
#define NROW 23040
#define KDIM 512
#define NCLS 7463
#define NCLSP 7680
#define NTILE_N 30
#define NTILE_M 180
#define O1_NZ 30
#define O1_KZ 512

typedef short s16x8 __attribute__((ext_vector_type(8)));
typedef short s16x4 __attribute__((ext_vector_type(4)));
typedef float f32x4 __attribute__((ext_vector_type(4)));

// ---- module-level scratch (every byte rewritten each call before any read) ----
__device__ unsigned short g_wc_hi[NCLSP * KDIM];
__device__ unsigned short g_wc_lo[NCLSP * KDIM];
__device__ unsigned short g_h_hi[NROW * KDIM];
__device__ unsigned short g_h_lo[NROW * KDIM];
__device__ unsigned short g_rawbf[NROW * 256];          // == [NSAMP][15360]
__device__ unsigned short g_wo1bf[512 * 15360];
__device__ float          g_pmax[NTILE_N * NROW];       // [nt][row]
__device__ int            g_pidx[NTILE_N * NROW];
__device__ float          g_part[O1_NZ * NSAMP * 512];

__device__ __forceinline__ float bf2f(unsigned short u){
  union { unsigned int i; float f; } v; v.i = ((unsigned int)u) << 16; return v.f;
}
__device__ __forceinline__ unsigned short f2bf(float f){
  union { float f; unsigned int i; } v; v.f = f;
  unsigned int u = v.i;
  unsigned int r = (u + 0x7FFFu + ((u >> 16) & 1u)) >> 16;
  return (unsigned short)r;
}
__device__ __forceinline__ void gload16(const void* g, void* l){
  __builtin_amdgcn_global_load_lds((const __attribute__((address_space(1))) void*)g,
                                   (__attribute__((address_space(3))) void*)l, 16, 0, 0);
}

// ---------------- K0: wc -> bf16 hi/lo (pad to 7680) AND wo1 -> bf16, one launch --
__global__ __launch_bounds__(256) void k_prep(const float* __restrict__ wc,
                                              const float* __restrict__ wo1)
{
  int b = blockIdx.x;
  if (b < 3840){
    int idx = (b * 256 + threadIdx.x) * 4;
    float4 w = {0.f, 0.f, 0.f, 0.f};
    if (idx < NCLS * KDIM) w = *(const float4*)(wc + idx);
    s16x4 hi, lo;
    float wv[4] = {w.x, w.y, w.z, w.w};
    #pragma unroll
    for (int i = 0; i < 4; ++i){
      unsigned short h = f2bf(wv[i]);
      hi[i] = (short)h;
      lo[i] = (short)f2bf(wv[i] - bf2f(h));
    }
    *(s16x4*)(g_wc_hi + idx) = hi;
    *(s16x4*)(g_wc_lo + idx) = lo;
  } else {
    int idx = ((b - 3840) * 256 + threadIdx.x) * 4;   // covers 512*15360 exactly
    float4 w = *(const float4*)(wo1 + idx);
    s16x4 v;
    v[0] = (short)f2bf(w.x); v[1] = (short)f2bf(w.y);
    v[2] = (short)f2bf(w.z); v[3] = (short)f2bf(w.w);
    *(s16x4*)(g_wo1bf + idx) = v;
  }
}

// ---------------- K1: per-combo features -> h hi/lo + raw bf16 ----------------
__global__ __launch_bounds__(256) void k_features(
    const int* __restrict__ x,
    const float* __restrict__ suit_w, const float* __restrict__ suit_b,
    const float* __restrict__ rank_w, const float* __restrict__ rank_b,
    const float* __restrict__ bns_g, const float* __restrict__ bns_b,
    const float* __restrict__ bns_m, const float* __restrict__ bns_v,
    const float* __restrict__ bnr_g, const float* __restrict__ bnr_b,
    const float* __restrict__ bnr_m, const float* __restrict__ bnr_v,
    const float* __restrict__ w1, const float* __restrict__ b1,
    const float* __restrict__ w2, const float* __restrict__ b2)
{
  __shared__ float raw_s[4][256];
  __shared__ float h1_s[4][512];
  const int tid  = threadIdx.x;
  const int lane = tid & 63;
  const int wv   = tid >> 6;
  const int combo = blockIdx.x * 4 + wv;
  const int s = combo / 60;
  const int k = combo % 60;
  const int hp = k / 10, bt = k % 10;
  const int HP0[6]  = {0,0,0,1,1,2}, HP1[6] = {1,2,3,2,3,3};
  const int BT0[10] = {4,4,4,4,4,4,5,5,5,6};
  const int BT1[10] = {5,5,5,6,6,7,6,6,7,7};
  const int BT2[10] = {6,7,8,7,8,8,7,8,8,8};
  int cards[5] = {HP0[hp], HP1[hp], BT0[bt], BT1[bt], BT2[bt]};
  const int* xp = x + s * 18;
  int rk[5], st[5];
  #pragma unroll
  for (int c = 0; c < 5; ++c){ rk[c] = xp[2*cards[c]]; st[c] = xp[2*cards[c] + 1]; }

  {
    s16x4 rv;
    #pragma unroll
    for (int i = 0; i < 4; ++i){
      int e = lane * 4 + i;
      int o = e >> 4, l = e & 15;
      float v;
      if (l < 11){
        float a = 0.f;
        #pragma unroll
        for (int c = 0; c < 5; ++c){
          int d = rk[c] - l;
          if (d >= 0 && d < 5) a += rank_w[o*25 + c*5 + d];
        }
        a += rank_b[o];
        float inv = bnr_g[o] / sqrtf(bnr_v[o] + 1e-5f);
        v = a * inv + (bnr_b[o] - bnr_m[o] * inv);
      } else {
        int j = l - 11;
        float a = suit_b[o];
        #pragma unroll
        for (int c = 0; c < 5; ++c) if (st[c] == j) a += suit_w[o*5 + c];
        float inv = bns_g[o] / sqrtf(bns_v[o] + 1e-5f);
        v = a * inv + (bns_b[o] - bns_m[o] * inv);
      }
      v = fmaxf(v, 0.f);
      raw_s[wv][e] = v;
      rv[i] = (short)f2bf(v);
    }
    *(s16x4*)(g_rawbf + (size_t)s * 15360 + k * 256 + lane * 4) = rv;
  }
  __syncthreads();
  #pragma unroll
  for (int i = 0; i < 8; ++i){
    int e = lane + 64 * i;
    int o = e >> 5, j = e & 31;
    float a = b1[j];
    #pragma unroll
    for (int l = 0; l < 16; ++l) a += raw_s[wv][o*16 + l] * w1[j*16 + l];
    h1_s[wv][e] = fmaxf(a, 0.f);
  }
  __syncthreads();
  {
    s16x8 hv, lv;
    #pragma unroll
    for (int i = 0; i < 8; ++i){
      int e = lane * 8 + i;
      int o = e >> 5, j = e & 31;
      float a = b2[j];
      #pragma unroll
      for (int l = 0; l < 32; ++l) a += h1_s[wv][o*32 + l] * w2[j*32 + l];
      a = fmaxf(a, 0.f);
      unsigned short h = f2bf(a);
      hv[i] = (short)h;
      lv[i] = (short)f2bf(a - bf2f(h));
    }
    *(s16x8*)(g_h_hi + (size_t)combo * 512 + lane * 8) = hv;
    *(s16x8*)(g_h_lo + (size_t)combo * 512 + lane * 8) = lv;
  }
}

// ---------------- K2: logits GEMM, virtual-K split, counted-vmcnt, 2 blocks/CU ----
// BM=128, BN=256, BK=32; 8 waves (2M x 4N), per-wave 64x64 out (acc=64 regs ->
// fits the 128-reg budget of __launch_bounds__(512,4) => 2 blocks/CU, 50% occ).
// Virtual K = 1536 interleaved k-first: t -> (kc=t/3*32, seg=t%3) so consecutive
// tiles reuse the same global k-slice (L2 hot). LDS 2 x 24KB dbuf; per tile 3
// gload_lds (A 8KB, B 16KB); loop waits vmcnt(3) (next tile ready, 3rd in
// flight) - never vmcnt(0) until the tail.
__global__ __launch_bounds__(512, 4) void k_logits(const float* __restrict__ bc)
{
  __shared__ unsigned char lds[49152];
  const int tid  = threadIdx.x;
  const int lane = tid & 63;
  const int wv   = tid >> 6;                 // 0..7
  const int wm   = wv >> 2, wn = wv & 3;     // 2M x 4N
  const int blk  = blockIdx.x;               // 5400 = 30 nt x 180 mt, m-fastest
  const int nt   = blk / NTILE_M;
  const int mt   = blk % NTILE_M;
  const int m0 = mt * 128;
  const int n0 = nt * 256;

  f32x4 acc[4][4];
  #pragma unroll
  for (int i = 0; i < 4; ++i)
    #pragma unroll
    for (int j = 0; j < 4; ++j)
      acc[i][j] = (f32x4){0.f, 0.f, 0.f, 0.f};

  // staging: A 128 rows (1 gload), B 256 rows (2 gloads). dest linear per wave:
  // base + wv*1024 + lane*16. source chunk inverse-swizzled so that reads with
  // chunk^=(row>>1)&3 see linear k (both-sides rule).
  const int rS = wv * 16 + (lane >> 2);              // 0..127
  const int cS = (lane & 3) ^ ((lane >> 3) & 3);     // pre-swizzled source chunk
  auto stage = [&](int buf, int t){
    const int p = t / 3, seg = t - p * 3;
    const int kc = p * 32;
    const unsigned short* As = (seg < 2) ? g_h_hi : g_h_lo;
    const unsigned short* Bs = (seg == 1) ? g_wc_lo : g_wc_hi;
    const unsigned base = buf * 24576 + wv * 1024;
    gload16(As + (size_t)(m0 + rS) * KDIM + kc + cS * 8, lds + base);
    gload16(Bs + (size_t)(n0 + rS) * KDIM + kc + cS * 8, lds + base + 8192);
    gload16(Bs + (size_t)(n0 + 128 + rS) * KDIM + kc + cS * 8, lds + base + 16384);
  };

  stage(0, 0);
  stage(1, 1);
  asm volatile("s_waitcnt vmcnt(3)" ::: "memory");   // tile0's 3 loads done
  __builtin_amdgcn_sched_barrier(0);
  __builtin_amdgcn_s_barrier();
  asm volatile("" ::: "memory");

  const int q = lane >> 4;                   // 16B k-chunk 0..3
  #pragma unroll 1
  for (int t = 0; t < 48; ++t){
    const unsigned cb = (unsigned)(t & 1) * 24576;
    s16x8 af[4], bf[4];
    #pragma unroll
    for (int i = 0; i < 4; ++i){
      int row = wm * 64 + i * 16 + (lane & 15);
      af[i] = *(const s16x8*)(lds + cb + row * 64 + ((q ^ ((row >> 1) & 3)) << 4));
    }
    #pragma unroll
    for (int j = 0; j < 4; ++j){
      int row = wn * 64 + j * 16 + (lane & 15);
      bf[j] = *(const s16x8*)(lds + cb + 8192 + row * 64 + ((q ^ ((row >> 1) & 3)) << 4));
    }
    __builtin_amdgcn_s_setprio(1);
    #pragma unroll
    for (int i = 0; i < 4; ++i)
      #pragma unroll
      for (int j = 0; j < 4; ++j)
        acc[i][j] = __builtin_amdgcn_mfma_f32_16x16x32_bf16(af[i], bf[j], acc[i][j], 0, 0, 0);
    __builtin_amdgcn_s_setprio(0);
    __builtin_amdgcn_sched_barrier(0);
    __builtin_amdgcn_s_barrier();            // all waves done reading buffer cb
    asm volatile("" ::: "memory");
    if (t + 2 < 48){
      stage(t & 1, t + 2);                   // overwrite cb; loads fly across barriers
      asm volatile("s_waitcnt vmcnt(3)" ::: "memory");  // tile t+1 confirmed
    } else {
      asm volatile("s_waitcnt vmcnt(0)" ::: "memory");  // tail drain
    }
    __builtin_amdgcn_sched_barrier(0);
    __builtin_amdgcn_s_barrier();
    asm volatile("" ::: "memory");
  }

  // epilogue: + bc, per-row argmax over this 256-col tile (ties -> lowest index)
  float* cmax = (float*)lds;                 // [128 rows][4 wn]
  int*   cidx = (int*)(lds + 2048);
  const int g = lane >> 4;
  #pragma unroll
  for (int i = 0; i < 4; ++i){
    #pragma unroll
    for (int r = 0; r < 4; ++r){
      float bv = -__builtin_inff(); int bi = 0x7FFFFFFF;
      #pragma unroll
      for (int j = 0; j < 4; ++j){
        int col = n0 + wn * 64 + j * 16 + (lane & 15);
        if (col < NCLS){
          float v = acc[i][j][r] + bc[col];
          if (v > bv){ bv = v; bi = col; }
        }
      }
      for (int s = 1; s < 16; s <<= 1){
        float ov = __shfl_xor(bv, s);
        int   oi = __shfl_xor(bi, s);
        if (ov > bv || (ov == bv && oi < bi)){ bv = ov; bi = oi; }
      }
      if ((lane & 15) == 0){
        int rloc = wm * 64 + i * 16 + g * 4 + r;
        cmax[rloc * 4 + wn] = bv;
        cidx[rloc * 4 + wn] = bi;
      }
    }
  }
  __syncthreads();
  if (tid < 128){
    float bv = cmax[tid * 4]; int bi = cidx[tid * 4];
    #pragma unroll
    for (int wq = 1; wq < 4; ++wq){
      float v = cmax[tid * 4 + wq]; int i1 = cidx[tid * 4 + wq];
      if (v > bv || (v == bv && i1 < bi)){ bv = v; bi = i1; }
    }
    size_t row = (size_t)(m0 + tid);
    g_pmax[(size_t)nt * NROW + row] = bv;
    g_pidx[(size_t)nt * NROW + row] = bi;
  }
}

// ---------------- K4: o-head first GEMM via MFMA (bf16), split-K z=30 -------------
__global__ __launch_bounds__(256) void k_o1(void)
{
  __shared__ unsigned char As[16384];
  __shared__ unsigned char Bs[16384];
  const int tid  = threadIdx.x;
  const int lane = tid & 63;
  const int wv   = tid >> 6;
  const int wr   = wv >> 1, wq = wv & 1;
  const int n0  = blockIdx.x * 128;
  const int m0  = blockIdx.y * 128;
  const int kc0 = blockIdx.z * O1_KZ;

  f32x4 acc[4][4];
  #pragma unroll
  for (int i = 0; i < 4; ++i)
    #pragma unroll
    for (int j = 0; j < 4; ++j)
      acc[i][j] = (f32x4){0.f, 0.f, 0.f, 0.f};

  const int rA = lane >> 3;
  const int c0 = lane & 7;
  for (int kk = 0; kk < O1_KZ; kk += 64){
    int kc = kc0 + kk;
    __syncthreads();
    #pragma unroll
    for (int it = 0; it < 4; ++it){
      int seg = wv * 4 + it;
      int r   = seg * 8 + rA;
      int cs  = c0 ^ (r & 7);
      gload16(g_rawbf + (size_t)(m0 + r) * 15360 + kc + cs * 8, As + seg * 1024);
      gload16(g_wo1bf + (size_t)(n0 + r) * 15360 + kc + cs * 8, Bs + seg * 1024);
    }
    __syncthreads();
    #pragma unroll
    for (int ks = 0; ks < 2; ++ks){
      int q = ks * 4 + (lane >> 4);
      s16x8 a[4];
      #pragma unroll
      for (int i = 0; i < 4; ++i){
        int row = wr * 64 + i * 16 + (lane & 15);
        a[i] = *(const s16x8*)(As + row * 128 + ((q ^ (row & 7)) * 16));
      }
      #pragma unroll
      for (int j = 0; j < 4; ++j){
        int col = wq * 64 + j * 16 + (lane & 15);
        s16x8 b = *(const s16x8*)(Bs + col * 128 + ((q ^ (col & 7)) * 16));
        #pragma unroll
        for (int i = 0; i < 4; ++i)
          acc[i][j] = __builtin_amdgcn_mfma_f32_16x16x32_bf16(a[i], b, acc[i][j], 0, 0, 0);
      }
    }
  }
  const int g = lane >> 4;
  #pragma unroll
  for (int i = 0; i < 4; ++i)
    #pragma unroll
    for (int j = 0; j < 4; ++j)
      #pragma unroll
      for (int r = 0; r < 4; ++r){
        int gm = m0 + wr * 64 + i * 16 + g * 4 + r;
        int gn = n0 + wq * 64 + j * 16 + (lane & 15);
        g_part[((size_t)blockIdx.z * NSAMP + gm) * 512 + gn] = acc[i][j][r];
      }
}

// ---------------- K5: tail: split-K reduce + 512->256->127 MLP + best-combine -----
__global__ __launch_bounds__(256) void k_tail(
    const float* __restrict__ bo1, const float* __restrict__ wo2,
    const float* __restrict__ bo2, const float* __restrict__ wo3,
    const float* __restrict__ bo3, float* __restrict__ out)
{
  __shared__ float o1f[512];
  __shared__ float o2f[256];
  __shared__ int   bis[60];
  const int s = blockIdx.x;
  const int tid = threadIdx.x;
  // best-index combine for this sample (independent of o-head)
  if (tid < 60){
    size_t row = (size_t)s * 60 + tid;
    float bv = -__builtin_inff(); int bi = 0x7FFFFFFF;
    for (int qn = 0; qn < NTILE_N; ++qn){
      float v = g_pmax[(size_t)qn * NROW + row];
      int   i = g_pidx[(size_t)qn * NROW + row];
      if (v > bv || (v == bv && i < bi)){ bv = v; bi = i; }
    }
    bis[tid] = bi;
  }
  for (int j = tid; j < 512; j += 256){
    float a = bo1[j];
    for (int ks = 0; ks < O1_NZ; ++ks) a += g_part[((size_t)ks * NSAMP + s) * 512 + j];
    o1f[j] = fmaxf(a, 0.f);
  }
  __syncthreads();
  {
    float a = bo2[tid];
    const float* wr = wo2 + (size_t)tid * 512;
    for (int i = 0; i < 512; i += 4){
      float4 w4 = *(const float4*)(wr + i);
      a += o1f[i]*w4.x + o1f[i+1]*w4.y + o1f[i+2]*w4.z + o1f[i+3]*w4.w;
    }
    o2f[tid] = fmaxf(a, 0.f);
  }
  __syncthreads();
  if (tid < 127){
    float a = bo3[tid];
    const float* wr = wo3 + (size_t)tid * 256;
    for (int i = 0; i < 256; i += 4){
      float4 w4 = *(const float4*)(wr + i);
      a += o2f[i]*w4.x + o2f[i+1]*w4.y + o2f[i+2]*w4.z + o2f[i+3]*w4.w;
    }
    out[s * 128 + tid] = fmaxf(a, 0.f);
  }
  if (tid == 0){
    int m = bis[0];
    for (int i = 1; i < 60; ++i) m = min(m, bis[i]);
    out[s * 128 + 127] = (float)m;
  }
}

extern "C" void kernel_launch(void* const* d_in, const int* in_sizes, int n_in,
                              void* d_out, int out_size, void* d_ws, size_t ws_size,
                              hipStream_t stream)
{
  (void)d_ws; (void)ws_size; (void)in_sizes; (void)n_in; (void)out_size;
  const int*   x      = (const int*)  d_in[0];
  const float* suit_w = (const float*)d_in[1];
  const float* suit_b = (const float*)d_in[2];
  const float* rank_w = (const float*)d_in[3];
  const float* rank_b = (const float*)d_in[4];
  const float* bns_g  = (const float*)d_in[5];
  const float* bns_b  = (const float*)d_in[6];
  const float* bns_m  = (const float*)d_in[7];
  const float* bns_v  = (const float*)d_in[8];
  const float* bnr_g  = (const float*)d_in[9];
  const float* bnr_b  = (const float*)d_in[10];
  const float* bnr_m  = (const float*)d_in[11];
  const float* bnr_v  = (const float*)d_in[12];
  const float* w1     = (const float*)d_in[13];
  const float* b1     = (const float*)d_in[14];
  const float* w2     = (const float*)d_in[15];
  const float* b2     = (const float*)d_in[16];
  const float* wc     = (const float*)d_in[17];
  const float* bc     = (const float*)d_in[18];
  const float* wo1    = (const float*)d_in[19];
  const float* bo1    = (const float*)d_in[20];
  const float* wo2    = (const float*)d_in[21];
  const float* bo2    = (const float*)d_in[22];
  const float* wo3    = (const float*)d_in[23];
  const float* bo3    = (const float*)d_in[24];
  float* out = (float*)d_out;

  hipLaunchKernelGGL(k_prep, dim3(11520), dim3(256), 0, stream, wc, wo1);
  hipLaunchKernelGGL(k_features, dim3(5760), dim3(256), 0, stream, x,
                     suit_w, suit_b, rank_w, rank_b,
                     bns_g, bns_b, bns_m, bns_v, bnr_g, bnr_b, bnr_m, bnr_v,
                     w1, b1, w2, b2);
  hipLaunchKernelGGL(k_logits, dim3(NTILE_N * NTILE_M), dim3(512), 0, stream, bc);
  hipLaunchKernelGGL(k_o1, dim3(4, 3, O1_NZ), dim3(256), 0, stream);
  hipLaunchKernelGGL(k_tail, dim3(NSAMP), dim3(256), 0, stream,
                     bo1, wo2, bo2, wo3, bo3, out);
}